// Round 8
// baseline (300.077 us; speedup 1.0000x reference)
//
#include <hip/hip_runtime.h>

typedef __bf16 bf16_t;
typedef __bf16 v8bf __attribute__((ext_vector_type(8)));
typedef __bf16 v4bf __attribute__((ext_vector_type(4)));
typedef float  v4f  __attribute__((ext_vector_type(4)));

#define D_MODEL 1024
#define NHEAD   16
#define DHEAD   64
#define SEQ     2048
#define BATCH   4
#define ROWS    (BATCH*SEQ)   // 8192

// async global->LDS, 16B per lane; LDS dest MUST be wave-uniform:
// HW writes base + lane*16 (guide §5: not a per-lane scatter).
#define GLD16(g, l) __builtin_amdgcn_global_load_lds( \
    (const __attribute__((address_space(1))) void*)(g), \
    (__attribute__((address_space(3))) void*)(l), 16, 0, 0)

#define BAR asm volatile("s_barrier" ::: "memory")

// ---------------------------------------------------------------- fused prep (casts + bias pack)
// grid-stride at 2048 blocks (R7: rest-budget -10us vs 12300 one-shot).
__global__ __launch_bounds__(256) void k_prep(const float* __restrict__ batch,
                                              const float* __restrict__ wq,
                                              const float* __restrict__ wk,
                                              const float* __restrict__ wv,
                                              const float* __restrict__ wo,
                                              const float* __restrict__ bq,
                                              const float* __restrict__ bk,
                                              const float* __restrict__ bv,
                                              bf16_t* __restrict__ Xb,
                                              bf16_t* __restrict__ Wqkv,
                                              bf16_t* __restrict__ Wob,
                                              float* __restrict__ bqkv) {
    int t = threadIdx.x;
    for (int bid = blockIdx.x; bid < 12300; bid += 2048) {
        const float* src; bf16_t* dst; int idx;
        if (bid < 8192)       { src = batch; dst = Xb;             idx = bid * 256 + t; }
        else if (bid < 9216)  { src = wq;    dst = Wqkv;           idx = (bid - 8192) * 256 + t; }
        else if (bid < 10240) { src = wk;    dst = Wqkv + 1048576; idx = (bid - 9216) * 256 + t; }
        else if (bid < 11264) { src = wv;    dst = Wqkv + 2097152; idx = (bid - 10240) * 256 + t; }
        else if (bid < 12288) { src = wo;    dst = Wob;            idx = (bid - 11264) * 256 + t; }
        else {
            int i = (bid - 12288) * 256 + t;   // 0..3071
            if (i < 1024) bqkv[i] = bq[i];
            else if (i < 2048) bqkv[i] = bk[i - 1024];
            else if (i < 3072) bqkv[i] = bv[i - 2048];
            continue;
        }
        float4 f = ((const float4*)src)[idx];
        v4bf o;
        o[0] = (bf16_t)f.x; o[1] = (bf16_t)f.y; o[2] = (bf16_t)f.z; o[3] = (bf16_t)f.w;
        ((v4bf*)dst)[idx] = o;
    }
}

// ---------------------------------------------------------------- 256x256 pipelined 4-phase GEMM (QKV)
// C = A * B^T (+bias, qmul on first 1024 cols). M=8192 N=3072 K=1024 HARDCODED.
// BM=BN=256, BK=64 (2 K-halves of 32), 512 thr = 8 waves, acc[8][4].
// LDS 128 KiB: As/Bs[2 tile-buf][2 K-half][256x32].
// Swizzle g(row)=(row>>1)&3 both sides (conflict-free, verified R6: 0).
// Fragment reads pipelined one phase ahead; one barrier/phase; counted
// vmcnt drains at P1/P3 (ledger verified R6). Unchanged this round.
__global__ __launch_bounds__(512, 2) void k_gemm256(
    const bf16_t* __restrict__ A, const bf16_t* __restrict__ Bm,
    const float* __restrict__ bias, bf16_t* __restrict__ C, float qmul)
{
    __shared__ bf16_t As[2][2][256 * 32];
    __shared__ bf16_t Bs[2][2][256 * 32];

    const int K = 1024;
    int bid = blockIdx.x;
    int wg = (bid & 7) * 48 + (bid >> 3);      // XCD-chunked: 384 = 8 x 48
    int m_idx = wg / 12, n_idx = wg % 12;
    int m0 = m_idx << 8, n0 = n_idx << 8;

    int t = threadIdx.x;
    int lane = t & 63, quad = lane >> 4, ln = lane & 15;
    int w = t >> 6, wr = w >> 2, wc = w & 3;

    int cl = (t & 3) ^ ((t >> 3) & 3);
    const bf16_t* Ag = A  + (size_t)(m0 + (t >> 2)) * K + cl * 8;
    const bf16_t* Bg = Bm + (size_t)(n0 + (t >> 2)) * K + cl * 8;
    int wb = w << 9;                            // wave-uniform LDS base

#define STA(bufv, khv, kc) { const bf16_t* g_ = Ag + (kc) + ((khv) << 5); \
    GLD16(g_, &As[bufv][khv][wb]); GLD16(g_ + 131072, &As[bufv][khv][wb + 4096]); }
#define STB(bufv, khv, kc) { const bf16_t* g_ = Bg + (kc) + ((khv) << 5); \
    GLD16(g_, &Bs[bufv][khv][wb]); GLD16(g_ + 131072, &Bs[bufv][khv][wb + 4096]); }

    int rsw = (quad ^ ((ln >> 1) & 3)) << 3;
    int aofs = (wr * 128 + ln) * 32 + rsw;
    int bofs = (wc * 64 + ln) * 32 + rsw;

#define LDA(dst, bufv, mhv) { \
    dst[0] = *(const v8bf*)&AB_[aofs + (mhv) * 2048]; \
    dst[1] = *(const v8bf*)&AB_[aofs + (mhv) * 2048 + 512]; \
    dst[2] = *(const v8bf*)&AB_[aofs + (mhv) * 2048 + 1024]; \
    dst[3] = *(const v8bf*)&AB_[aofs + (mhv) * 2048 + 1536]; }
#define LDAF(dst, bufv, khv, mhv) { const bf16_t* AB_ = &As[bufv][khv][0]; LDA(dst, bufv, mhv) }
#define LDBF(dst, bufv, khv) { const bf16_t* BB_ = &Bs[bufv][khv][0]; \
    dst[0] = *(const v8bf*)&BB_[bofs]; \
    dst[1] = *(const v8bf*)&BB_[bofs + 512]; \
    dst[2] = *(const v8bf*)&BB_[bofs + 1024]; \
    dst[3] = *(const v8bf*)&BB_[bofs + 1536]; }

    v4f acc[8][4];
#pragma unroll
    for (int i = 0; i < 8; i++)
#pragma unroll
        for (int j = 0; j < 4; j++) acc[i][j] = (v4f){0.f, 0.f, 0.f, 0.f};

    v8bf aX[4], aY[4], bX[4], bY[4];

#define MF(AC, BC, M0) \
    __builtin_amdgcn_s_setprio(1); \
    acc[(M0)+0][0] = __builtin_amdgcn_mfma_f32_16x16x32_bf16(AC[0], BC[0], acc[(M0)+0][0], 0, 0, 0); \
    acc[(M0)+0][1] = __builtin_amdgcn_mfma_f32_16x16x32_bf16(AC[0], BC[1], acc[(M0)+0][1], 0, 0, 0); \
    acc[(M0)+0][2] = __builtin_amdgcn_mfma_f32_16x16x32_bf16(AC[0], BC[2], acc[(M0)+0][2], 0, 0, 0); \
    acc[(M0)+0][3] = __builtin_amdgcn_mfma_f32_16x16x32_bf16(AC[0], BC[3], acc[(M0)+0][3], 0, 0, 0); \
    acc[(M0)+1][0] = __builtin_amdgcn_mfma_f32_16x16x32_bf16(AC[1], BC[0], acc[(M0)+1][0], 0, 0, 0); \
    acc[(M0)+1][1] = __builtin_amdgcn_mfma_f32_16x16x32_bf16(AC[1], BC[1], acc[(M0)+1][1], 0, 0, 0); \
    acc[(M0)+1][2] = __builtin_amdgcn_mfma_f32_16x16x32_bf16(AC[1], BC[2], acc[(M0)+1][2], 0, 0, 0); \
    acc[(M0)+1][3] = __builtin_amdgcn_mfma_f32_16x16x32_bf16(AC[1], BC[3], acc[(M0)+1][3], 0, 0, 0); \
    acc[(M0)+2][0] = __builtin_amdgcn_mfma_f32_16x16x32_bf16(AC[2], BC[0], acc[(M0)+2][0], 0, 0, 0); \
    acc[(M0)+2][1] = __builtin_amdgcn_mfma_f32_16x16x32_bf16(AC[2], BC[1], acc[(M0)+2][1], 0, 0, 0); \
    acc[(M0)+2][2] = __builtin_amdgcn_mfma_f32_16x16x32_bf16(AC[2], BC[2], acc[(M0)+2][2], 0, 0, 0); \
    acc[(M0)+2][3] = __builtin_amdgcn_mfma_f32_16x16x32_bf16(AC[2], BC[3], acc[(M0)+2][3], 0, 0, 0); \
    acc[(M0)+3][0] = __builtin_amdgcn_mfma_f32_16x16x32_bf16(AC[3], BC[0], acc[(M0)+3][0], 0, 0, 0); \
    acc[(M0)+3][1] = __builtin_amdgcn_mfma_f32_16x16x32_bf16(AC[3], BC[1], acc[(M0)+3][1], 0, 0, 0); \
    acc[(M0)+3][2] = __builtin_amdgcn_mfma_f32_16x16x32_bf16(AC[3], BC[2], acc[(M0)+3][2], 0, 0, 0); \
    acc[(M0)+3][3] = __builtin_amdgcn_mfma_f32_16x16x32_bf16(AC[3], BC[3], acc[(M0)+3][3], 0, 0, 0); \
    __builtin_amdgcn_s_setprio(0);

#define TAIL_W6 { asm volatile("s_waitcnt vmcnt(6)" ::: "memory"); BAR; __builtin_amdgcn_sched_barrier(0); }
#define TAIL_W4 { asm volatile("s_waitcnt vmcnt(4)" ::: "memory"); BAR; __builtin_amdgcn_sched_barrier(0); }
#define TAIL_W0 { asm volatile("s_waitcnt vmcnt(0)" ::: "memory"); BAR; __builtin_amdgcn_sched_barrier(0); }
#define TAIL_B  { BAR; __builtin_amdgcn_sched_barrier(0); }

    // prologue: A/B(t0)kh0, A/B(t0)kh1, A/B(t1)kh0 (12 loads)
    STA(0, 0, 0); STB(0, 0, 0);
    STA(0, 1, 0); STB(0, 1, 0);
    STA(1, 0, 64); STB(1, 0, 64);
    asm volatile("s_waitcnt vmcnt(8)" ::: "memory");   // t0.kh0 landed
    BAR; __builtin_amdgcn_sched_barrier(0);
    LDAF(aX, 0, 0, 0); LDBF(bX, 0, 0);                 // frags for t0 P1

#define TILE(b, kc, S1, S2, S3, S4, T1, T3, P4B, P4LD) \
    S1; LDAF(aY, b, 0, 1);                    MF(aX, bX, 0); T1; \
    S2; LDBF(bY, b, 1); LDAF(aX, b, 1, 0);    MF(aY, bX, 4); TAIL_B; \
    S3; LDAF(aY, b, 1, 1);                    MF(aX, bY, 0); T3; \
    S4; if (P4LD) { LDBF(bX, P4B, 0); LDAF(aX, P4B, 0, 0); } \
                                              MF(aY, bY, 4); TAIL_B;

    int kb = 0;
#pragma unroll 1
    for (int tp = 0; tp < 7; ++tp, kb += 128) {
        TILE(0, kb, STA(1, 1, kb + 64), STB(1, 1, kb + 64),
                    STA(0, 0, kb + 128), STB(0, 0, kb + 128),
                    TAIL_W6, TAIL_W6, 1, 1)
        TILE(1, kb + 64, STA(0, 1, kb + 128), STB(0, 1, kb + 128),
                         STA(1, 0, kb + 192), STB(1, 0, kb + 192),
                         TAIL_W6, TAIL_W6, 0, 1)
    }
    TILE(0, 896, STA(1, 1, 960), STB(1, 1, 960), , ,
                 TAIL_W6, TAIL_W4, 1, 1)
    { const int b = 1;
      LDAF(aY, b, 0, 1);                    MF(aX, bX, 0); TAIL_W0;
      LDBF(bY, b, 1); LDAF(aX, b, 1, 0);    MF(aY, bX, 4); TAIL_B;
      LDAF(aY, b, 1, 1);                    MF(aX, bY, 0); TAIL_B;
                                            MF(aY, bY, 4);
    }

#undef TILE
#undef MF
#undef TAIL_W6
#undef TAIL_W4
#undef TAIL_W0
#undef TAIL_B
#undef LDA
#undef LDAF
#undef LDBF
#undef STA
#undef STB

#pragma unroll
    for (int m = 0; m < 8; m++) {
#pragma unroll
        for (int r = 0; r < 4; r++) {
            int row = m0 + wr * 128 + m * 16 + quad * 4 + r;
#pragma unroll
            for (int n = 0; n < 4; n++) {
                int col = n0 + wc * 64 + n * 16 + ln;
                float v = acc[m][n][r] + bias[col];
                if (col < 1024) v *= qmul;
                C[(size_t)row * 3072 + col] = (bf16_t)v;
            }
        }
    }
}

// ---------------------------------------------------------------- GEMM  C = A * B^T (+bias) (+resid)
// proj GEMM: REVERTED to the R1 2-buffer 32KB __syncthreads structure.
// Rest-budget analysis (R1 138us -> R2 152.7us) showed the 3-buffer/48KB
// variant cost ~14us here: at grid 512 (2 blocks/CU of work) the extra
// buffer buys nothing while the LDS bump cuts co-residency.
__global__ __launch_bounds__(256, 3) void k_gemm_bt(
    const bf16_t* __restrict__ A, const bf16_t* __restrict__ Bm,
    const float* __restrict__ bias, const float* __restrict__ resid,
    bf16_t* __restrict__ Cb, float* __restrict__ Cf,
    int M, int N, int K, int qcols, float qmul)
{
    __shared__ bf16_t As[2][128 * 32];
    __shared__ bf16_t Bs[2][128 * 32];

    int nTile = N >> 7;
    int x = blockIdx.x & 7, g = blockIdx.x >> 3;
    int n_idx = g % nTile;
    int m_idx = (g / nTile) * 8 + x;
    int m0 = m_idx << 7;
    int n0 = n_idx << 7;
    int t = threadIdx.x;
    int w = t >> 6, lane = t & 63, quad = lane >> 4, ln = lane & 15;
    int wm = (w >> 1) << 6, wn = (w & 1) << 6;

    int srow = lane >> 2;                               // 0..15
    int scol = ((lane & 3) ^ ((lane >> 3) & 3)) << 3;   // swizzled logical chunk *8
    const bf16_t* Ag0 = A  + (size_t)(m0 + w * 16 +      srow) * K + scol;
    const bf16_t* Ag1 = A  + (size_t)(m0 + w * 16 + 64 + srow) * K + scol;
    const bf16_t* Bg0 = Bm + (size_t)(n0 + w * 16 +      srow) * K + scol;
    const bf16_t* Bg1 = Bm + (size_t)(n0 + w * 16 + 64 + srow) * K + scol;
    int lo0 = (w * 16) * 32, lo1 = (w * 16 + 64) * 32;

    v4f acc[4][4];
#pragma unroll
    for (int i = 0; i < 4; i++)
#pragma unroll
        for (int j = 0; j < 4; j++) acc[i][j] = (v4f){0.f, 0.f, 0.f, 0.f};

    // prologue: tile 0 -> buf 0
    GLD16(Ag0, &As[0][lo0]);
    GLD16(Ag1, &As[0][lo1]);
    GLD16(Bg0, &Bs[0][lo0]);
    GLD16(Bg1, &Bs[0][lo1]);

    int sw = (ln >> 1) & 3;   // read-side swizzle
    int buf = 0;
    for (int k0 = 0; k0 < K; k0 += 32, buf ^= 1) {
        __syncthreads();   // vmcnt(0) drain covers tile-k0 loads (in flight since k0-32)
        if (k0 + 32 < K) {
            GLD16(Ag0 + k0 + 32, &As[buf ^ 1][lo0]);
            GLD16(Ag1 + k0 + 32, &As[buf ^ 1][lo1]);
            GLD16(Bg0 + k0 + 32, &Bs[buf ^ 1][lo0]);
            GLD16(Bg1 + k0 + 32, &Bs[buf ^ 1][lo1]);
        }
        v8bf af[4], bfr[4];
#pragma unroll
        for (int mt = 0; mt < 4; mt++)
            af[mt] = *(const v8bf*)&As[buf][(wm + mt * 16 + ln) * 32 + ((quad ^ sw) << 3)];
#pragma unroll
        for (int nt = 0; nt < 4; nt++)
            bfr[nt] = *(const v8bf*)&Bs[buf][(wn + nt * 16 + ln) * 32 + ((quad ^ sw) << 3)];
#pragma unroll
        for (int mt = 0; mt < 4; mt++)
#pragma unroll
            for (int nt = 0; nt < 4; nt++)
                acc[mt][nt] = __builtin_amdgcn_mfma_f32_16x16x32_bf16(af[mt], bfr[nt], acc[mt][nt], 0, 0, 0);
    }

#pragma unroll
    for (int mt = 0; mt < 4; mt++) {
#pragma unroll
        for (int r = 0; r < 4; r++) {
            int row = m0 + wm + mt * 16 + quad * 4 + r;
#pragma unroll
            for (int nt = 0; nt < 4; nt++) {
                int col = n0 + wn + nt * 16 + ln;
                float v = acc[mt][nt][r] + bias[col];
                if (Cf) Cf[(size_t)row * N + col] = v + resid[(size_t)row * N + col];
                else {
                    if (col < qcols) v *= qmul;
                    Cb[(size_t)row * N + col] = (bf16_t)v;
                }
            }
        }
    }
}

// ---------------------------------------------------------------- V transpose: qkv V-cols -> Vt[bh][d][s]
__global__ __launch_bounds__(256) void k_transpose_v(const bf16_t* __restrict__ qkv,
                                                     bf16_t* __restrict__ vt) {
    __shared__ bf16_t tile[64 * 72];
    int bid = blockIdx.x;
    int st = bid & 31, bh = bid >> 5, b = bh >> 4, h = bh & 15;
    int t = threadIdx.x;
    const bf16_t* src = qkv + (size_t)(b * SEQ + st * 64) * 3072 + 2048 + h * 64;
#pragma unroll
    for (int i = 0; i < 2; i++) {
        int c = t + i * 256, row = c >> 3, c8 = (c & 7) << 3;
        *(uint4*)&tile[row * 72 + c8] = *(const uint4*)(src + (size_t)row * 3072 + c8);
    }
    __syncthreads();
    bf16_t* dst = vt + (size_t)bh * DHEAD * SEQ + st * 64;
#pragma unroll
    for (int i = 0; i < 2; i++) {
        int c = t + i * 256, d = c >> 3, s8 = (c & 7) << 3;
        v8bf o;
#pragma unroll
        for (int j = 0; j < 8; j++) o[j] = tile[(s8 + j) * 72 + d];
        *(v8bf*)(dst + (size_t)d * SEQ + s8) = o;
    }
}

// ---------------------------------------------------------------- attention (register-resident P)
// R8: reverted to __launch_bounds__(256, 2) -- the (256,4) request was
// null-to-negative (R7: 74.1 vs R6: 72.5, occupancy unchanged 31%).
// Body unchanged (K/V swizzles conflict-free, verified R6: 0 conflicts).
__global__ __launch_bounds__(256, 2) void k_attn(const bf16_t* __restrict__ qkv,
                                                 const bf16_t* __restrict__ vt,
                                                 bf16_t* __restrict__ attn) {
    __shared__ bf16_t Ks[2][64 * 64];
    __shared__ bf16_t Vs[2][64 * 64];

    int bid = blockIdx.x;
    int xcd = bid & 7, g = bid >> 3;
    int qt = g & 15;
    int bh = ((g >> 4) << 3) | xcd;
    int b = bh >> 4, h = bh & 15;
    int t = threadIdx.x, w = t >> 6, lane = t & 63, quad = lane >> 4, ln = lane & 15;
    int q0 = qt * 128 + w * 32;

    v8bf qf[2][2];
#pragma unroll
    for (int qs = 0; qs < 2; qs++) {
        const bf16_t* Qp = qkv + (size_t)(b * SEQ + q0 + qs * 16 + ln) * 3072 + h * 64 + quad * 8;
        qf[qs][0] = *(const v8bf*)Qp;
        qf[qs][1] = *(const v8bf*)(Qp + 32);
    }

    int srow = lane >> 3;                        // 0..7
    int scolK = ((lane & 7) ^ ((lane >> 3) & 3) ^ ((w & 1) << 2)) << 3;
    int scolV = ((lane & 7) ^ (lane >> 3)) << 3;
    const bf16_t* Kg0 = qkv + (size_t)(b * SEQ + w * 8 +      srow) * 3072 + 1024 + h * 64 + scolK;
    const bf16_t* Kg1 = qkv + (size_t)(b * SEQ + w * 8 + 32 + srow) * 3072 + 1024 + h * 64 + scolK;
    const bf16_t* Vg0 = vt + (size_t)bh * DHEAD * SEQ + (size_t)(w * 8 +      srow) * SEQ + scolV;
    const bf16_t* Vg1 = vt + (size_t)bh * DHEAD * SEQ + (size_t)(w * 8 + 32 + srow) * SEQ + scolV;
    int ko0 = (w * 8) * 64, ko1 = (w * 8 + 32) * 64;

    int gk = (ln & 3) | (((ln >> 2) & 1) << 2);
    int gv = ln & 7;
    int rrbase = ((ln >> 2) << 3) + (ln & 3);
    int o0 = (rrbase) * 64,       o1 = (rrbase + 4) * 64;
    int o2 = (rrbase + 32) * 64,  o3 = (rrbase + 36) * 64;

    const v4f z4 = (v4f){0.f, 0.f, 0.f, 0.f};
    v8bf ones8;
#pragma unroll
    for (int j = 0; j < 8; j++) ones8[j] = (bf16_t)1.0f;

    v4f o[2][4];
#pragma unroll
    for (int qs = 0; qs < 2; qs++)
#pragma unroll
        for (int d = 0; d < 4; d++) o[qs][d] = z4;
    v4f den[2] = {z4, z4};

    GLD16(Kg0, &Ks[0][ko0]);
    GLD16(Kg1, &Ks[0][ko1]);
    GLD16(Vg0, &Vs[0][ko0]);
    GLD16(Vg1, &Vs[0][ko1]);

    int buf = 0;
    for (int kt = 0; kt < SEQ; kt += 64, buf ^= 1) {
        __syncthreads();
        if (kt + 64 < SEQ) {
            GLD16(Kg0 + (size_t)(kt + 64) * 3072, &Ks[buf ^ 1][ko0]);
            GLD16(Kg1 + (size_t)(kt + 64) * 3072, &Ks[buf ^ 1][ko1]);
            GLD16(Vg0 + kt + 64, &Vs[buf ^ 1][ko0]);
            GLD16(Vg1 + kt + 64, &Vs[buf ^ 1][ko1]);
        }

        const bf16_t* Kb = &Ks[buf][0];
        v4f s0[4], s1[4];
        int rof[4] = {o0, o1, o2, o3};
#pragma unroll
        for (int nt = 0; nt < 4; nt++) {
            v8bf kf0 = *(const v8bf*)&Kb[rof[nt] + ((quad ^ gk) << 3)];
            v8bf kf1 = *(const v8bf*)&Kb[rof[nt] + (((quad | 4) ^ gk) << 3)];
            s0[nt] = __builtin_amdgcn_mfma_f32_16x16x32_bf16(kf0, qf[0][0], z4, 0, 0, 0);
            s0[nt] = __builtin_amdgcn_mfma_f32_16x16x32_bf16(kf1, qf[0][1], s0[nt], 0, 0, 0);
            s1[nt] = __builtin_amdgcn_mfma_f32_16x16x32_bf16(kf0, qf[1][0], z4, 0, 0, 0);
            s1[nt] = __builtin_amdgcn_mfma_f32_16x16x32_bf16(kf1, qf[1][1], s1[nt], 0, 0, 0);
        }

#pragma unroll
        for (int tk = 0; tk < 2; tk++) {
            v8bf vfd[4];
#pragma unroll
            for (int d = 0; d < 4; d++)
                vfd[d] = *(const v8bf*)&Vs[buf][(d * 16 + ln) * 64 + (((tk * 4 + quad) ^ gv) << 3)];
#pragma unroll
            for (int qs = 0; qs < 2; qs++) {
                v4f* s = qs ? s1 : s0;
                float e0 = __builtin_amdgcn_exp2f(s[2 * tk][0]);
                float e1 = __builtin_amdgcn_exp2f(s[2 * tk][1]);
                float e2 = __builtin_amdgcn_exp2f(s[2 * tk][2]);
                float e3 = __builtin_amdgcn_exp2f(s[2 * tk][3]);
                float e4 = __builtin_amdgcn_exp2f(s[2 * tk + 1][0]);
                float e5 = __builtin_amdgcn_exp2f(s[2 * tk + 1][1]);
                float e6 = __builtin_amdgcn_exp2f(s[2 * tk + 1][2]);
                float e7 = __builtin_amdgcn_exp2f(s[2 * tk + 1][3]);
                v8bf pf;
                pf[0] = (bf16_t)e0; pf[1] = (bf16_t)e1; pf[2] = (bf16_t)e2; pf[3] = (bf16_t)e3;
                pf[4] = (bf16_t)e4; pf[5] = (bf16_t)e5; pf[6] = (bf16_t)e6; pf[7] = (bf16_t)e7;
                den[qs] = __builtin_amdgcn_mfma_f32_16x16x32_bf16(pf, ones8, den[qs], 0, 0, 0);
#pragma unroll
                for (int d = 0; d < 4; d++)
                    o[qs][d] = __builtin_amdgcn_mfma_f32_16x16x32_bf16(pf, vfd[d], o[qs][d], 0, 0, 0);
            }
        }
    }

#pragma unroll
    for (int qs = 0; qs < 2; qs++) {
        int rowg = b * SEQ + q0 + qs * 16;
#pragma unroll
        for (int r = 0; r < 4; r++) {
            float inv = 1.f / den[qs][r];
#pragma unroll
            for (int d = 0; d < 4; d++)
                attn[(size_t)(rowg + quad * 4 + r) * D_MODEL + h * 64 + d * 16 + ln] =
                    (bf16_t)(o[qs][d][r] * inv);
        }
    }
}

// ---------------------------------------------------------------- LayerNorm (one row / block)
__global__ __launch_bounds__(256) void k_layernorm(const float* __restrict__ y,
                                                   const float* __restrict__ g,
                                                   const float* __restrict__ beta,
                                                   float* __restrict__ out) {
    __shared__ float rs[4], rq[4];
    int row = blockIdx.x, t = threadIdx.x;
    int w = t >> 6, lane = t & 63;
    float4 v = ((const float4*)(y + (size_t)row * D_MODEL))[t];
    float s = v.x + v.y + v.z + v.w;
    float q = v.x * v.x + v.y * v.y + v.z * v.z + v.w * v.w;
#pragma unroll
    for (int off = 1; off < 64; off <<= 1) {
        s += __shfl_xor(s, off);
        q += __shfl_xor(q, off);
    }
    if (lane == 0) { rs[w] = s; rq[w] = q; }
    __syncthreads();
    s = rs[0] + rs[1] + rs[2] + rs[3];
    q = rq[0] + rq[1] + rq[2] + rq[3];
    float mu = s * (1.f / D_MODEL);
    float var = q * (1.f / D_MODEL) - mu * mu;
    float rstd = rsqrtf(var + 1e-5f);
    float4 gg = ((const float4*)g)[t];
    float4 bb = ((const float4*)beta)[t];
    float4 o;
    o.x = (v.x - mu) * rstd * gg.x + bb.x;
    o.y = (v.y - mu) * rstd * gg.y + bb.y;
    o.z = (v.z - mu) * rstd * gg.z + bb.z;
    o.w = (v.w - mu) * rstd * gg.w + bb.w;
    ((float4*)(out + (size_t)row * D_MODEL))[t] = o;
}

// ---------------------------------------------------------------- launch
extern "C" void kernel_launch(void* const* d_in, const int* in_sizes, int n_in,
                              void* d_out, int out_size, void* d_ws, size_t ws_size,
                              hipStream_t stream) {
    const float* batch = (const float*)d_in[0];
    const float* wq = (const float*)d_in[1];
    const float* bq = (const float*)d_in[2];
    const float* wk = (const float*)d_in[3];
    const float* bk = (const float*)d_in[4];
    const float* wv = (const float*)d_in[5];
    const float* bv = (const float*)d_in[6];
    const float* wo = (const float*)d_in[7];
    const float* bo = (const float*)d_in[8];
    const float* ln_g = (const float*)d_in[9];
    const float* ln_b = (const float*)d_in[10];
    float* out = (float*)d_out;

    char* ws = (char*)d_ws;
    size_t offXb   = 0;                                          // bf16 X (later Vt)
    size_t offWqkv = offXb + (size_t)ROWS * D_MODEL * 2;
    size_t offWo   = offWqkv + (size_t)3072 * 1024 * 2;
    size_t offBias = offWo + (size_t)1024 * 1024 * 2;
    size_t offQKV  = offBias + 3072 * 4;                         // bf16 qkv (later fp32 y)
    size_t offAttn = offQKV + (size_t)ROWS * 3072 * 2;
    size_t total   = offAttn + (size_t)ROWS * D_MODEL * 2;       // = 92,286,976
    if (ws_size < total) return;

    bf16_t* Xb   = (bf16_t*)(ws + offXb);
    bf16_t* Vt   = (bf16_t*)(ws + offXb);
    bf16_t* Wqkv = (bf16_t*)(ws + offWqkv);
    bf16_t* Wob  = (bf16_t*)(ws + offWo);
    float*  bqkv = (float*)(ws + offBias);
    bf16_t* qkv  = (bf16_t*)(ws + offQKV);
    float*  y    = (float*)(ws + offQKV);
    bf16_t* attn = (bf16_t*)(ws + offAttn);

    const float SC = 0.125f * 1.44269504088896f;  // 1/sqrt(64) * log2(e), folded into Q

    k_prep<<<2048, 256, 0, stream>>>(batch, wq, wk, wv, wo, bq, bk, bv,
                                     Xb, Wqkv, Wob, bqkv);
    k_gemm256<<<384, 512, 0, stream>>>(Xb, Wqkv, bqkv, qkv, SC);
    k_transpose_v<<<2048, 256, 0, stream>>>(qkv, Vt);
    k_attn<<<1024, 256, 0, stream>>>(qkv, Vt, attn);
    k_gemm_bt<<<64 * 8, 256, 0, stream>>>(attn, Wob, bo, batch, nullptr, y,
                                          8192, 1024, 1024, 0, 1.0f);
    k_layernorm<<<8192, 256, 0, stream>>>(y, ln_g, ln_b, out);
}

// Round 9
// 294.000 us; speedup vs baseline: 1.0207x; 1.0207x over previous
//
#include <hip/hip_runtime.h>

typedef __bf16 bf16_t;
typedef __bf16 v8bf __attribute__((ext_vector_type(8)));
typedef __bf16 v4bf __attribute__((ext_vector_type(4)));
typedef float  v4f  __attribute__((ext_vector_type(4)));

#define D_MODEL 1024
#define NHEAD   16
#define DHEAD   64
#define SEQ     2048
#define BATCH   4
#define ROWS    (BATCH*SEQ)   // 8192

// async global->LDS, 16B per lane; LDS dest MUST be wave-uniform:
// HW writes base + lane*16 (guide §5: not a per-lane scatter).
#define GLD16(g, l) __builtin_amdgcn_global_load_lds( \
    (const __attribute__((address_space(1))) void*)(g), \
    (__attribute__((address_space(3))) void*)(l), 16, 0, 0)

#define BAR asm volatile("s_barrier" ::: "memory")

// ---------------------------------------------------------------- fused prep (casts + bias pack)
// grid-stride at 2048 blocks.
__global__ __launch_bounds__(256) void k_prep(const float* __restrict__ batch,
                                              const float* __restrict__ wq,
                                              const float* __restrict__ wk,
                                              const float* __restrict__ wv,
                                              const float* __restrict__ wo,
                                              const float* __restrict__ bq,
                                              const float* __restrict__ bk,
                                              const float* __restrict__ bv,
                                              bf16_t* __restrict__ Xb,
                                              bf16_t* __restrict__ Wqkv,
                                              bf16_t* __restrict__ Wob,
                                              float* __restrict__ bqkv) {
    int t = threadIdx.x;
    for (int bid = blockIdx.x; bid < 12300; bid += 2048) {
        const float* src; bf16_t* dst; int idx;
        if (bid < 8192)       { src = batch; dst = Xb;             idx = bid * 256 + t; }
        else if (bid < 9216)  { src = wq;    dst = Wqkv;           idx = (bid - 8192) * 256 + t; }
        else if (bid < 10240) { src = wk;    dst = Wqkv + 1048576; idx = (bid - 9216) * 256 + t; }
        else if (bid < 11264) { src = wv;    dst = Wqkv + 2097152; idx = (bid - 10240) * 256 + t; }
        else if (bid < 12288) { src = wo;    dst = Wob;            idx = (bid - 11264) * 256 + t; }
        else {
            int i = (bid - 12288) * 256 + t;   // 0..3071
            if (i < 1024) bqkv[i] = bq[i];
            else if (i < 2048) bqkv[i] = bk[i - 1024];
            else if (i < 3072) bqkv[i] = bv[i - 2048];
            continue;
        }
        float4 f = ((const float4*)src)[idx];
        v4bf o;
        o[0] = (bf16_t)f.x; o[1] = (bf16_t)f.y; o[2] = (bf16_t)f.z; o[3] = (bf16_t)f.w;
        ((v4bf*)dst)[idx] = o;
    }
}

// ---------------------------------------------------------------- 256x256 pipelined 4-phase GEMM (QKV)
// Unchanged (R6 structure; 0 conflicts, ledger verified).
__global__ __launch_bounds__(512, 2) void k_gemm256(
    const bf16_t* __restrict__ A, const bf16_t* __restrict__ Bm,
    const float* __restrict__ bias, bf16_t* __restrict__ C, float qmul)
{
    __shared__ bf16_t As[2][2][256 * 32];
    __shared__ bf16_t Bs[2][2][256 * 32];

    const int K = 1024;
    int bid = blockIdx.x;
    int wg = (bid & 7) * 48 + (bid >> 3);      // XCD-chunked: 384 = 8 x 48
    int m_idx = wg / 12, n_idx = wg % 12;
    int m0 = m_idx << 8, n0 = n_idx << 8;

    int t = threadIdx.x;
    int lane = t & 63, quad = lane >> 4, ln = lane & 15;
    int w = t >> 6, wr = w >> 2, wc = w & 3;

    int cl = (t & 3) ^ ((t >> 3) & 3);
    const bf16_t* Ag = A  + (size_t)(m0 + (t >> 2)) * K + cl * 8;
    const bf16_t* Bg = Bm + (size_t)(n0 + (t >> 2)) * K + cl * 8;
    int wb = w << 9;                            // wave-uniform LDS base

#define STA(bufv, khv, kc) { const bf16_t* g_ = Ag + (kc) + ((khv) << 5); \
    GLD16(g_, &As[bufv][khv][wb]); GLD16(g_ + 131072, &As[bufv][khv][wb + 4096]); }
#define STB(bufv, khv, kc) { const bf16_t* g_ = Bg + (kc) + ((khv) << 5); \
    GLD16(g_, &Bs[bufv][khv][wb]); GLD16(g_ + 131072, &Bs[bufv][khv][wb + 4096]); }

    int rsw = (quad ^ ((ln >> 1) & 3)) << 3;
    int aofs = (wr * 128 + ln) * 32 + rsw;
    int bofs = (wc * 64 + ln) * 32 + rsw;

#define LDA(dst, bufv, mhv) { \
    dst[0] = *(const v8bf*)&AB_[aofs + (mhv) * 2048]; \
    dst[1] = *(const v8bf*)&AB_[aofs + (mhv) * 2048 + 512]; \
    dst[2] = *(const v8bf*)&AB_[aofs + (mhv) * 2048 + 1024]; \
    dst[3] = *(const v8bf*)&AB_[aofs + (mhv) * 2048 + 1536]; }
#define LDAF(dst, bufv, khv, mhv) { const bf16_t* AB_ = &As[bufv][khv][0]; LDA(dst, bufv, mhv) }
#define LDBF(dst, bufv, khv) { const bf16_t* BB_ = &Bs[bufv][khv][0]; \
    dst[0] = *(const v8bf*)&BB_[bofs]; \
    dst[1] = *(const v8bf*)&BB_[bofs + 512]; \
    dst[2] = *(const v8bf*)&BB_[bofs + 1024]; \
    dst[3] = *(const v8bf*)&BB_[bofs + 1536]; }

    v4f acc[8][4];
#pragma unroll
    for (int i = 0; i < 8; i++)
#pragma unroll
        for (int j = 0; j < 4; j++) acc[i][j] = (v4f){0.f, 0.f, 0.f, 0.f};

    v8bf aX[4], aY[4], bX[4], bY[4];

#define MF(AC, BC, M0) \
    __builtin_amdgcn_s_setprio(1); \
    acc[(M0)+0][0] = __builtin_amdgcn_mfma_f32_16x16x32_bf16(AC[0], BC[0], acc[(M0)+0][0], 0, 0, 0); \
    acc[(M0)+0][1] = __builtin_amdgcn_mfma_f32_16x16x32_bf16(AC[0], BC[1], acc[(M0)+0][1], 0, 0, 0); \
    acc[(M0)+0][2] = __builtin_amdgcn_mfma_f32_16x16x32_bf16(AC[0], BC[2], acc[(M0)+0][2], 0, 0, 0); \
    acc[(M0)+0][3] = __builtin_amdgcn_mfma_f32_16x16x32_bf16(AC[0], BC[3], acc[(M0)+0][3], 0, 0, 0); \
    acc[(M0)+1][0] = __builtin_amdgcn_mfma_f32_16x16x32_bf16(AC[1], BC[0], acc[(M0)+1][0], 0, 0, 0); \
    acc[(M0)+1][1] = __builtin_amdgcn_mfma_f32_16x16x32_bf16(AC[1], BC[1], acc[(M0)+1][1], 0, 0, 0); \
    acc[(M0)+1][2] = __builtin_amdgcn_mfma_f32_16x16x32_bf16(AC[1], BC[2], acc[(M0)+1][2], 0, 0, 0); \
    acc[(M0)+1][3] = __builtin_amdgcn_mfma_f32_16x16x32_bf16(AC[1], BC[3], acc[(M0)+1][3], 0, 0, 0); \
    acc[(M0)+2][0] = __builtin_amdgcn_mfma_f32_16x16x32_bf16(AC[2], BC[0], acc[(M0)+2][0], 0, 0, 0); \
    acc[(M0)+2][1] = __builtin_amdgcn_mfma_f32_16x16x32_bf16(AC[2], BC[1], acc[(M0)+2][1], 0, 0, 0); \
    acc[(M0)+2][2] = __builtin_amdgcn_mfma_f32_16x16x32_bf16(AC[2], BC[2], acc[(M0)+2][2], 0, 0, 0); \
    acc[(M0)+2][3] = __builtin_amdgcn_mfma_f32_16x16x32_bf16(AC[2], BC[3], acc[(M0)+2][3], 0, 0, 0); \
    acc[(M0)+3][0] = __builtin_amdgcn_mfma_f32_16x16x32_bf16(AC[3], BC[0], acc[(M0)+3][0], 0, 0, 0); \
    acc[(M0)+3][1] = __builtin_amdgcn_mfma_f32_16x16x32_bf16(AC[3], BC[1], acc[(M0)+3][1], 0, 0, 0); \
    acc[(M0)+3][2] = __builtin_amdgcn_mfma_f32_16x16x32_bf16(AC[3], BC[2], acc[(M0)+3][2], 0, 0, 0); \
    acc[(M0)+3][3] = __builtin_amdgcn_mfma_f32_16x16x32_bf16(AC[3], BC[3], acc[(M0)+3][3], 0, 0, 0); \
    __builtin_amdgcn_s_setprio(0);

#define TAIL_W6 { asm volatile("s_waitcnt vmcnt(6)" ::: "memory"); BAR; __builtin_amdgcn_sched_barrier(0); }
#define TAIL_W4 { asm volatile("s_waitcnt vmcnt(4)" ::: "memory"); BAR; __builtin_amdgcn_sched_barrier(0); }
#define TAIL_W0 { asm volatile("s_waitcnt vmcnt(0)" ::: "memory"); BAR; __builtin_amdgcn_sched_barrier(0); }
#define TAIL_B  { BAR; __builtin_amdgcn_sched_barrier(0); }

    // prologue: A/B(t0)kh0, A/B(t0)kh1, A/B(t1)kh0 (12 loads)
    STA(0, 0, 0); STB(0, 0, 0);
    STA(0, 1, 0); STB(0, 1, 0);
    STA(1, 0, 64); STB(1, 0, 64);
    asm volatile("s_waitcnt vmcnt(8)" ::: "memory");   // t0.kh0 landed
    BAR; __builtin_amdgcn_sched_barrier(0);
    LDAF(aX, 0, 0, 0); LDBF(bX, 0, 0);                 // frags for t0 P1

#define TILE(b, kc, S1, S2, S3, S4, T1, T3, P4B, P4LD) \
    S1; LDAF(aY, b, 0, 1);                    MF(aX, bX, 0); T1; \
    S2; LDBF(bY, b, 1); LDAF(aX, b, 1, 0);    MF(aY, bX, 4); TAIL_B; \
    S3; LDAF(aY, b, 1, 1);                    MF(aX, bY, 0); T3; \
    S4; if (P4LD) { LDBF(bX, P4B, 0); LDAF(aX, P4B, 0, 0); } \
                                              MF(aY, bY, 4); TAIL_B;

    int kb = 0;
#pragma unroll 1
    for (int tp = 0; tp < 7; ++tp, kb += 128) {
        TILE(0, kb, STA(1, 1, kb + 64), STB(1, 1, kb + 64),
                    STA(0, 0, kb + 128), STB(0, 0, kb + 128),
                    TAIL_W6, TAIL_W6, 1, 1)
        TILE(1, kb + 64, STA(0, 1, kb + 128), STB(0, 1, kb + 128),
                         STA(1, 0, kb + 192), STB(1, 0, kb + 192),
                         TAIL_W6, TAIL_W6, 0, 1)
    }
    TILE(0, 896, STA(1, 1, 960), STB(1, 1, 960), , ,
                 TAIL_W6, TAIL_W4, 1, 1)
    { const int b = 1;
      LDAF(aY, b, 0, 1);                    MF(aX, bX, 0); TAIL_W0;
      LDBF(bY, b, 1); LDAF(aX, b, 1, 0);    MF(aY, bX, 4); TAIL_B;
      LDAF(aY, b, 1, 1);                    MF(aX, bY, 0); TAIL_B;
                                            MF(aY, bY, 4);
    }

#undef TILE
#undef MF
#undef TAIL_W6
#undef TAIL_W4
#undef TAIL_W0
#undef TAIL_B
#undef LDA
#undef LDAF
#undef LDBF
#undef STA
#undef STB

#pragma unroll
    for (int m = 0; m < 8; m++) {
#pragma unroll
        for (int r = 0; r < 4; r++) {
            int row = m0 + wr * 128 + m * 16 + quad * 4 + r;
#pragma unroll
            for (int n = 0; n < 4; n++) {
                int col = n0 + wc * 64 + n * 16 + ln;
                float v = acc[m][n][r] + bias[col];
                if (col < 1024) v *= qmul;
                C[(size_t)row * 3072 + col] = (bf16_t)v;
            }
        }
    }
}

// ---------------------------------------------------------------- GEMM  C = A * B^T (+bias) (+resid)
// proj GEMM: R1 2-buffer 32KB __syncthreads structure (R8 confirmed ~parity).
__global__ __launch_bounds__(256, 3) void k_gemm_bt(
    const bf16_t* __restrict__ A, const bf16_t* __restrict__ Bm,
    const float* __restrict__ bias, const float* __restrict__ resid,
    bf16_t* __restrict__ Cb, float* __restrict__ Cf,
    int M, int N, int K, int qcols, float qmul)
{
    __shared__ bf16_t As[2][128 * 32];
    __shared__ bf16_t Bs[2][128 * 32];

    int nTile = N >> 7;
    int x = blockIdx.x & 7, g = blockIdx.x >> 3;
    int n_idx = g % nTile;
    int m_idx = (g / nTile) * 8 + x;
    int m0 = m_idx << 7;
    int n0 = n_idx << 7;
    int t = threadIdx.x;
    int w = t >> 6, lane = t & 63, quad = lane >> 4, ln = lane & 15;
    int wm = (w >> 1) << 6, wn = (w & 1) << 6;

    int srow = lane >> 2;                               // 0..15
    int scol = ((lane & 3) ^ ((lane >> 3) & 3)) << 3;   // swizzled logical chunk *8
    const bf16_t* Ag0 = A  + (size_t)(m0 + w * 16 +      srow) * K + scol;
    const bf16_t* Ag1 = A  + (size_t)(m0 + w * 16 + 64 + srow) * K + scol;
    const bf16_t* Bg0 = Bm + (size_t)(n0 + w * 16 +      srow) * K + scol;
    const bf16_t* Bg1 = Bm + (size_t)(n0 + w * 16 + 64 + srow) * K + scol;
    int lo0 = (w * 16) * 32, lo1 = (w * 16 + 64) * 32;

    v4f acc[4][4];
#pragma unroll
    for (int i = 0; i < 4; i++)
#pragma unroll
        for (int j = 0; j < 4; j++) acc[i][j] = (v4f){0.f, 0.f, 0.f, 0.f};

    // prologue: tile 0 -> buf 0
    GLD16(Ag0, &As[0][lo0]);
    GLD16(Ag1, &As[0][lo1]);
    GLD16(Bg0, &Bs[0][lo0]);
    GLD16(Bg1, &Bs[0][lo1]);

    int sw = (ln >> 1) & 3;   // read-side swizzle
    int buf = 0;
    for (int k0 = 0; k0 < K; k0 += 32, buf ^= 1) {
        __syncthreads();   // vmcnt(0) drain covers tile-k0 loads (in flight since k0-32)
        if (k0 + 32 < K) {
            GLD16(Ag0 + k0 + 32, &As[buf ^ 1][lo0]);
            GLD16(Ag1 + k0 + 32, &As[buf ^ 1][lo1]);
            GLD16(Bg0 + k0 + 32, &Bs[buf ^ 1][lo0]);
            GLD16(Bg1 + k0 + 32, &Bs[buf ^ 1][lo1]);
        }
        v8bf af[4], bfr[4];
#pragma unroll
        for (int mt = 0; mt < 4; mt++)
            af[mt] = *(const v8bf*)&As[buf][(wm + mt * 16 + ln) * 32 + ((quad ^ sw) << 3)];
#pragma unroll
        for (int nt = 0; nt < 4; nt++)
            bfr[nt] = *(const v8bf*)&Bs[buf][(wn + nt * 16 + ln) * 32 + ((quad ^ sw) << 3)];
#pragma unroll
        for (int mt = 0; mt < 4; mt++)
#pragma unroll
            for (int nt = 0; nt < 4; nt++)
                acc[mt][nt] = __builtin_amdgcn_mfma_f32_16x16x32_bf16(af[mt], bfr[nt], acc[mt][nt], 0, 0, 0);
    }

#pragma unroll
    for (int mt = 0; mt < 4; mt++) {
#pragma unroll
        for (int r = 0; r < 4; r++) {
            int row = m0 + wm + mt * 16 + quad * 4 + r;
#pragma unroll
            for (int nt = 0; nt < 4; nt++) {
                int col = n0 + wn + nt * 16 + ln;
                float v = acc[mt][nt][r] + bias[col];
                if (Cf) Cf[(size_t)row * N + col] = v + resid[(size_t)row * N + col];
                else {
                    if (col < qcols) v *= qmul;
                    Cb[(size_t)row * N + col] = (bf16_t)v;
                }
            }
        }
    }
}

// ---------------------------------------------------------------- V transpose: qkv V-cols -> Vt[bh][d][s]
__global__ __launch_bounds__(256) void k_transpose_v(const bf16_t* __restrict__ qkv,
                                                     bf16_t* __restrict__ vt) {
    __shared__ bf16_t tile[64 * 72];
    int bid = blockIdx.x;
    int st = bid & 31, bh = bid >> 5, b = bh >> 4, h = bh & 15;
    int t = threadIdx.x;
    const bf16_t* src = qkv + (size_t)(b * SEQ + st * 64) * 3072 + 2048 + h * 64;
#pragma unroll
    for (int i = 0; i < 2; i++) {
        int c = t + i * 256, row = c >> 3, c8 = (c & 7) << 3;
        *(uint4*)&tile[row * 72 + c8] = *(const uint4*)(src + (size_t)row * 3072 + c8);
    }
    __syncthreads();
    bf16_t* dst = vt + (size_t)bh * DHEAD * SEQ + st * 64;
#pragma unroll
    for (int i = 0; i < 2; i++) {
        int c = t + i * 256, d = c >> 3, s8 = (c & 7) << 3;
        v8bf o;
#pragma unroll
        for (int j = 0; j < 8; j++) o[j] = tile[(s8 + j) * 72 + d];
        *(v8bf*)(dst + (size_t)d * SEQ + s8) = o;
    }
}

// ---------------------------------------------------------------- attention (register-resident P)
// R9: 2 q-tiles per block -- 512 thr = 8 waves, each wave its original
// 32-q-row role (q0 = qt8*256 + w*32); K/V tile (unchanged 64x64 each,
// 32KB total) staged ONCE per 256 q-rows (2x less staging work) and
// shared by 8 waves. 2 blocks/CU => 16 waves/CU (2x R8's 8) for better
// MFMA/VALU cross-wave interleave (kernel is 88% combined-issue-bound at
// occupancy 30%). Grid 512 = 8 xcd x 8 bh-grp x 8 qt8, balanced 2/CU;
// per-XCD K/V set 8 bh x 512KB = 4MB = L2 (unchanged).
// Staging remap (verified): thread t covers tile-row w*8 + (lane>>3),
// phys chunk lane&7; K swizzle g(row)=(row&3)|((row>>3&1)<<2) =>
// ((lane>>3)&3) ^ ((w&1)<<2) per-lane; V swizzle g(d)=d&7 => lane>>3.
// One GLD16/thread for K, one for V per tile (512 thr x 16B = 8KB each).
// Read-side offsets w-independent (unchanged from R8's verified body).
__global__ __launch_bounds__(512, 2) void k_attn(const bf16_t* __restrict__ qkv,
                                                 const bf16_t* __restrict__ vt,
                                                 bf16_t* __restrict__ attn) {
    __shared__ bf16_t Ks[2][64 * 64];
    __shared__ bf16_t Vs[2][64 * 64];

    int bid = blockIdx.x;
    int xcd = bid & 7, u = bid >> 3;
    int qt8 = u & 7;                    // 8 q-tiles of 256 rows
    int bh = ((u >> 3) << 3) | xcd;     // 8 bh-groups x 8 xcd = 64 bh
    int b = bh >> 4, h = bh & 15;
    int t = threadIdx.x, w = t >> 6, lane = t & 63, quad = lane >> 4, ln = lane & 15;
    int q0 = qt8 * 256 + w * 32;

    v8bf qf[2][2];
#pragma unroll
    for (int qs = 0; qs < 2; qs++) {
        const bf16_t* Qp = qkv + (size_t)(b * SEQ + q0 + qs * 16 + ln) * 3072 + h * 64 + quad * 8;
        qf[qs][0] = *(const v8bf*)Qp;
        qf[qs][1] = *(const v8bf*)(Qp + 32);
    }

    // staging: thread t covers tile-row tr = w*8 + (lane>>3), chunk lane&7
    int tr = w * 8 + (lane >> 3);
    int scolK = ((lane & 7) ^ ((lane >> 3) & 3) ^ ((w & 1) << 2)) << 3;
    int scolV = ((lane & 7) ^ (lane >> 3)) << 3;
    const bf16_t* Kg = qkv + (size_t)(b * SEQ + tr) * 3072 + 1024 + h * 64 + scolK;
    const bf16_t* Vg = vt + (size_t)bh * DHEAD * SEQ + (size_t)tr * SEQ + scolV;
    int ko = (w * 8) * 64;              // wave-uniform LDS base (elements)

    int gk = (ln & 3) | (((ln >> 2) & 1) << 2);
    int gv = ln & 7;
    int rrbase = ((ln >> 2) << 3) + (ln & 3);
    int o0 = (rrbase) * 64,       o1 = (rrbase + 4) * 64;
    int o2 = (rrbase + 32) * 64,  o3 = (rrbase + 36) * 64;

    const v4f z4 = (v4f){0.f, 0.f, 0.f, 0.f};
    v8bf ones8;
#pragma unroll
    for (int j = 0; j < 8; j++) ones8[j] = (bf16_t)1.0f;

    v4f o[2][4];
#pragma unroll
    for (int qs = 0; qs < 2; qs++)
#pragma unroll
        for (int d = 0; d < 4; d++) o[qs][d] = z4;
    v4f den[2] = {z4, z4};

    // prologue: tile 0 -> buf 0 (1 GLD16 K + 1 GLD16 V per thread)
    GLD16(Kg, &Ks[0][ko]);
    GLD16(Vg, &Vs[0][ko]);

    int buf = 0;
    for (int kt = 0; kt < SEQ; kt += 64, buf ^= 1) {
        __syncthreads();
        if (kt + 64 < SEQ) {
            GLD16(Kg + (size_t)(kt + 64) * 3072, &Ks[buf ^ 1][ko]);
            GLD16(Vg + kt + 64, &Vs[buf ^ 1][ko]);
        }

        const bf16_t* Kb = &Ks[buf][0];
        v4f s0[4], s1[4];
        int rof[4] = {o0, o1, o2, o3};
#pragma unroll
        for (int nt = 0; nt < 4; nt++) {
            v8bf kf0 = *(const v8bf*)&Kb[rof[nt] + ((quad ^ gk) << 3)];
            v8bf kf1 = *(const v8bf*)&Kb[rof[nt] + (((quad | 4) ^ gk) << 3)];
            s0[nt] = __builtin_amdgcn_mfma_f32_16x16x32_bf16(kf0, qf[0][0], z4, 0, 0, 0);
            s0[nt] = __builtin_amdgcn_mfma_f32_16x16x32_bf16(kf1, qf[0][1], s0[nt], 0, 0, 0);
            s1[nt] = __builtin_amdgcn_mfma_f32_16x16x32_bf16(kf0, qf[1][0], z4, 0, 0, 0);
            s1[nt] = __builtin_amdgcn_mfma_f32_16x16x32_bf16(kf1, qf[1][1], s1[nt], 0, 0, 0);
        }

#pragma unroll
        for (int tk = 0; tk < 2; tk++) {
            v8bf vfd[4];
#pragma unroll
            for (int d = 0; d < 4; d++)
                vfd[d] = *(const v8bf*)&Vs[buf][(d * 16 + ln) * 64 + (((tk * 4 + quad) ^ gv) << 3)];
#pragma unroll
            for (int qs = 0; qs < 2; qs++) {
                v4f* s = qs ? s1 : s0;
                float e0 = __builtin_amdgcn_exp2f(s[2 * tk][0]);
                float e1 = __builtin_amdgcn_exp2f(s[2 * tk][1]);
                float e2 = __builtin_amdgcn_exp2f(s[2 * tk][2]);
                float e3 = __builtin_amdgcn_exp2f(s[2 * tk][3]);
                float e4 = __builtin_amdgcn_exp2f(s[2 * tk + 1][0]);
                float e5 = __builtin_amdgcn_exp2f(s[2 * tk + 1][1]);
                float e6 = __builtin_amdgcn_exp2f(s[2 * tk + 1][2]);
                float e7 = __builtin_amdgcn_exp2f(s[2 * tk + 1][3]);
                v8bf pf;
                pf[0] = (bf16_t)e0; pf[1] = (bf16_t)e1; pf[2] = (bf16_t)e2; pf[3] = (bf16_t)e3;
                pf[4] = (bf16_t)e4; pf[5] = (bf16_t)e5; pf[6] = (bf16_t)e6; pf[7] = (bf16_t)e7;
                den[qs] = __builtin_amdgcn_mfma_f32_16x16x32_bf16(pf, ones8, den[qs], 0, 0, 0);
#pragma unroll
                for (int d = 0; d < 4; d++)
                    o[qs][d] = __builtin_amdgcn_mfma_f32_16x16x32_bf16(pf, vfd[d], o[qs][d], 0, 0, 0);
            }
        }
    }

#pragma unroll
    for (int qs = 0; qs < 2; qs++) {
        int rowg = b * SEQ + q0 + qs * 16;
#pragma unroll
        for (int r = 0; r < 4; r++) {
            float inv = 1.f / den[qs][r];
#pragma unroll
            for (int d = 0; d < 4; d++)
                attn[(size_t)(rowg + quad * 4 + r) * D_MODEL + h * 64 + d * 16 + ln] =
                    (bf16_t)(o[qs][d][r] * inv);
        }
    }
}

// ---------------------------------------------------------------- LayerNorm (one row / block)
__global__ __launch_bounds__(256) void k_layernorm(const float* __restrict__ y,
                                                   const float* __restrict__ g,
                                                   const float* __restrict__ beta,
                                                   float* __restrict__ out) {
    __shared__ float rs[4], rq[4];
    int row = blockIdx.x, t = threadIdx.x;
    int w = t >> 6, lane = t & 63;
    float4 v = ((const float4*)(y + (size_t)row * D_MODEL))[t];
    float s = v.x + v.y + v.z + v.w;
    float q = v.x * v.x + v.y * v.y + v.z * v.z + v.w * v.w;
#pragma unroll
    for (int off = 1; off < 64; off <<= 1) {
        s += __shfl_xor(s, off);
        q += __shfl_xor(q, off);
    }
    if (lane == 0) { rs[w] = s; rq[w] = q; }
    __syncthreads();
    s = rs[0] + rs[1] + rs[2] + rs[3];
    q = rq[0] + rq[1] + rq[2] + rq[3];
    float mu = s * (1.f / D_MODEL);
    float var = q * (1.f / D_MODEL) - mu * mu;
    float rstd = rsqrtf(var + 1e-5f);
    float4 gg = ((const float4*)g)[t];
    float4 bb = ((const float4*)beta)[t];
    float4 o;
    o.x = (v.x - mu) * rstd * gg.x + bb.x;
    o.y = (v.y - mu) * rstd * gg.y + bb.y;
    o.z = (v.z - mu) * rstd * gg.z + bb.z;
    o.w = (v.w - mu) * rstd * gg.w + bb.w;
    ((float4*)(out + (size_t)row * D_MODEL))[t] = o;
}

// ---------------------------------------------------------------- launch
extern "C" void kernel_launch(void* const* d_in, const int* in_sizes, int n_in,
                              void* d_out, int out_size, void* d_ws, size_t ws_size,
                              hipStream_t stream) {
    const float* batch = (const float*)d_in[0];
    const float* wq = (const float*)d_in[1];
    const float* bq = (const float*)d_in[2];
    const float* wk = (const float*)d_in[3];
    const float* bk = (const float*)d_in[4];
    const float* wv = (const float*)d_in[5];
    const float* bv = (const float*)d_in[6];
    const float* wo = (const float*)d_in[7];
    const float* bo = (const float*)d_in[8];
    const float* ln_g = (const float*)d_in[9];
    const float* ln_b = (const float*)d_in[10];
    float* out = (float*)d_out;

    char* ws = (char*)d_ws;
    size_t offXb   = 0;                                          // bf16 X (later Vt)
    size_t offWqkv = offXb + (size_t)ROWS * D_MODEL * 2;
    size_t offWo   = offWqkv + (size_t)3072 * 1024 * 2;
    size_t offBias = offWo + (size_t)1024 * 1024 * 2;
    size_t offQKV  = offBias + 3072 * 4;                         // bf16 qkv (later fp32 y)
    size_t offAttn = offQKV + (size_t)ROWS * 3072 * 2;
    size_t total   = offAttn + (size_t)ROWS * D_MODEL * 2;       // = 92,286,976
    if (ws_size < total) return;

    bf16_t* Xb   = (bf16_t*)(ws + offXb);
    bf16_t* Vt   = (bf16_t*)(ws + offXb);
    bf16_t* Wqkv = (bf16_t*)(ws + offWqkv);
    bf16_t* Wob  = (bf16_t*)(ws + offWo);
    float*  bqkv = (float*)(ws + offBias);
    bf16_t* qkv  = (bf16_t*)(ws + offQKV);
    float*  y    = (float*)(ws + offQKV);
    bf16_t* attn = (bf16_t*)(ws + offAttn);

    const float SC = 0.125f * 1.44269504088896f;  // 1/sqrt(64) * log2(e), folded into Q

    k_prep<<<2048, 256, 0, stream>>>(batch, wq, wk, wv, wo, bq, bk, bv,
                                     Xb, Wqkv, Wob, bqkv);
    k_gemm256<<<384, 512, 0, stream>>>(Xb, Wqkv, bqkv, qkv, SC);
    k_transpose_v<<<2048, 256, 0, stream>>>(qkv, Vt);
    k_attn<<<512, 512, 0, stream>>>(qkv, Vt, attn);
    k_gemm_bt<<<64 * 8, 256, 0, stream>>>(attn, Wob, bo, batch, nullptr, y,
                                          8192, 1024, 1024, 0, 1.0f);
    k_layernorm<<<8192, 256, 0, stream>>>(y, ln_g, ln_b, out);
}

// Round 10
// 289.126 us; speedup vs baseline: 1.0379x; 1.0169x over previous
//
#include <hip/hip_runtime.h>

typedef __bf16 bf16_t;
typedef __bf16 v8bf __attribute__((ext_vector_type(8)));
typedef __bf16 v4bf __attribute__((ext_vector_type(4)));
typedef float  v4f  __attribute__((ext_vector_type(4)));

#define D_MODEL 1024
#define NHEAD   16
#define DHEAD   64
#define SEQ     2048
#define BATCH   4
#define ROWS    (BATCH*SEQ)   // 8192

// async global->LDS, 16B per lane; LDS dest MUST be wave-uniform:
// HW writes base + lane*16 (guide §5: not a per-lane scatter).
#define GLD16(g, l) __builtin_amdgcn_global_load_lds( \
    (const __attribute__((address_space(1))) void*)(g), \
    (__attribute__((address_space(3))) void*)(l), 16, 0, 0)

#define BAR asm volatile("s_barrier" ::: "memory")

// ---------------------------------------------------------------- fused prep (casts + bias pack)
// grid-stride at 2048 blocks.
__global__ __launch_bounds__(256) void k_prep(const float* __restrict__ batch,
                                              const float* __restrict__ wq,
                                              const float* __restrict__ wk,
                                              const float* __restrict__ wv,
                                              const float* __restrict__ wo,
                                              const float* __restrict__ bq,
                                              const float* __restrict__ bk,
                                              const float* __restrict__ bv,
                                              bf16_t* __restrict__ Xb,
                                              bf16_t* __restrict__ Wqkv,
                                              bf16_t* __restrict__ Wob,
                                              float* __restrict__ bqkv) {
    int t = threadIdx.x;
    for (int bid = blockIdx.x; bid < 12300; bid += 2048) {
        const float* src; bf16_t* dst; int idx;
        if (bid < 8192)       { src = batch; dst = Xb;             idx = bid * 256 + t; }
        else if (bid < 9216)  { src = wq;    dst = Wqkv;           idx = (bid - 8192) * 256 + t; }
        else if (bid < 10240) { src = wk;    dst = Wqkv + 1048576; idx = (bid - 9216) * 256 + t; }
        else if (bid < 11264) { src = wv;    dst = Wqkv + 2097152; idx = (bid - 10240) * 256 + t; }
        else if (bid < 12288) { src = wo;    dst = Wob;            idx = (bid - 11264) * 256 + t; }
        else {
            int i = (bid - 12288) * 256 + t;   // 0..3071
            if (i < 1024) bqkv[i] = bq[i];
            else if (i < 2048) bqkv[i] = bk[i - 1024];
            else if (i < 3072) bqkv[i] = bv[i - 2048];
            continue;
        }
        float4 f = ((const float4*)src)[idx];
        v4bf o;
        o[0] = (bf16_t)f.x; o[1] = (bf16_t)f.y; o[2] = (bf16_t)f.z; o[3] = (bf16_t)f.w;
        ((v4bf*)dst)[idx] = o;
    }
}

// ---------------------------------------------------------------- 256x256 pipelined GEMM (QKV)
// R10: barrier audit -- P2-tail and P4-tail barriers PROVEN redundant:
//  * W-after-R: any stage targeting region X issues after the wave passed
//    the P1-tail (resp. P3-tail) barrier; all other waves' reads of X
//    complete before their same barrier -> 1-barrier separation holds.
//  * R-after-W: per-thread FIFO at (t)P1-tail vmcnt(6) leaves exactly
//    {t+1kh0 A,B; t+1kh1 A} -> [t,kh1] drained for P2/P3 reads; at
//    (t)P3-tail leaves {t+1kh1 A,B; t+2kh0 A} -> [t+1,kh0] drained for
//    P4 reads. Cross-wave: own-vmcnt-then-barrier publishes writes.
// => 2 barriers/tile (was 4), and the scheduler may overlap P2-MFMA with
// P3 reads / P4-MFMA with next-P1 reads (fences removed with them).
// vmcnt ledger unchanged (verified R6); swizzle conflict-free (R6: 0).
__global__ __launch_bounds__(512, 2) void k_gemm256(
    const bf16_t* __restrict__ A, const bf16_t* __restrict__ Bm,
    const float* __restrict__ bias, bf16_t* __restrict__ C, float qmul)
{
    __shared__ bf16_t As[2][2][256 * 32];
    __shared__ bf16_t Bs[2][2][256 * 32];

    const int K = 1024;
    int bid = blockIdx.x;
    int wg = (bid & 7) * 48 + (bid >> 3);      // XCD-chunked: 384 = 8 x 48
    int m_idx = wg / 12, n_idx = wg % 12;
    int m0 = m_idx << 8, n0 = n_idx << 8;

    int t = threadIdx.x;
    int lane = t & 63, quad = lane >> 4, ln = lane & 15;
    int w = t >> 6, wr = w >> 2, wc = w & 3;

    int cl = (t & 3) ^ ((t >> 3) & 3);
    const bf16_t* Ag = A  + (size_t)(m0 + (t >> 2)) * K + cl * 8;
    const bf16_t* Bg = Bm + (size_t)(n0 + (t >> 2)) * K + cl * 8;
    int wb = w << 9;                            // wave-uniform LDS base

#define STA(bufv, khv, kc) { const bf16_t* g_ = Ag + (kc) + ((khv) << 5); \
    GLD16(g_, &As[bufv][khv][wb]); GLD16(g_ + 131072, &As[bufv][khv][wb + 4096]); }
#define STB(bufv, khv, kc) { const bf16_t* g_ = Bg + (kc) + ((khv) << 5); \
    GLD16(g_, &Bs[bufv][khv][wb]); GLD16(g_ + 131072, &Bs[bufv][khv][wb + 4096]); }

    int rsw = (quad ^ ((ln >> 1) & 3)) << 3;
    int aofs = (wr * 128 + ln) * 32 + rsw;
    int bofs = (wc * 64 + ln) * 32 + rsw;

#define LDA(dst, bufv, mhv) { \
    dst[0] = *(const v8bf*)&AB_[aofs + (mhv) * 2048]; \
    dst[1] = *(const v8bf*)&AB_[aofs + (mhv) * 2048 + 512]; \
    dst[2] = *(const v8bf*)&AB_[aofs + (mhv) * 2048 + 1024]; \
    dst[3] = *(const v8bf*)&AB_[aofs + (mhv) * 2048 + 1536]; }
#define LDAF(dst, bufv, khv, mhv) { const bf16_t* AB_ = &As[bufv][khv][0]; LDA(dst, bufv, mhv) }
#define LDBF(dst, bufv, khv) { const bf16_t* BB_ = &Bs[bufv][khv][0]; \
    dst[0] = *(const v8bf*)&BB_[bofs]; \
    dst[1] = *(const v8bf*)&BB_[bofs + 512]; \
    dst[2] = *(const v8bf*)&BB_[bofs + 1024]; \
    dst[3] = *(const v8bf*)&BB_[bofs + 1536]; }

    v4f acc[8][4];
#pragma unroll
    for (int i = 0; i < 8; i++)
#pragma unroll
        for (int j = 0; j < 4; j++) acc[i][j] = (v4f){0.f, 0.f, 0.f, 0.f};

    v8bf aX[4], aY[4], bX[4], bY[4];

#define MF(AC, BC, M0) \
    __builtin_amdgcn_s_setprio(1); \
    acc[(M0)+0][0] = __builtin_amdgcn_mfma_f32_16x16x32_bf16(AC[0], BC[0], acc[(M0)+0][0], 0, 0, 0); \
    acc[(M0)+0][1] = __builtin_amdgcn_mfma_f32_16x16x32_bf16(AC[0], BC[1], acc[(M0)+0][1], 0, 0, 0); \
    acc[(M0)+0][2] = __builtin_amdgcn_mfma_f32_16x16x32_bf16(AC[0], BC[2], acc[(M0)+0][2], 0, 0, 0); \
    acc[(M0)+0][3] = __builtin_amdgcn_mfma_f32_16x16x32_bf16(AC[0], BC[3], acc[(M0)+0][3], 0, 0, 0); \
    acc[(M0)+1][0] = __builtin_amdgcn_mfma_f32_16x16x32_bf16(AC[1], BC[0], acc[(M0)+1][0], 0, 0, 0); \
    acc[(M0)+1][1] = __builtin_amdgcn_mfma_f32_16x16x32_bf16(AC[1], BC[1], acc[(M0)+1][1], 0, 0, 0); \
    acc[(M0)+1][2] = __builtin_amdgcn_mfma_f32_16x16x32_bf16(AC[1], BC[2], acc[(M0)+1][2], 0, 0, 0); \
    acc[(M0)+1][3] = __builtin_amdgcn_mfma_f32_16x16x32_bf16(AC[1], BC[3], acc[(M0)+1][3], 0, 0, 0); \
    acc[(M0)+2][0] = __builtin_amdgcn_mfma_f32_16x16x32_bf16(AC[2], BC[0], acc[(M0)+2][0], 0, 0, 0); \
    acc[(M0)+2][1] = __builtin_amdgcn_mfma_f32_16x16x32_bf16(AC[2], BC[1], acc[(M0)+2][1], 0, 0, 0); \
    acc[(M0)+2][2] = __builtin_amdgcn_mfma_f32_16x16x32_bf16(AC[2], BC[2], acc[(M0)+2][2], 0, 0, 0); \
    acc[(M0)+2][3] = __builtin_amdgcn_mfma_f32_16x16x32_bf16(AC[2], BC[3], acc[(M0)+2][3], 0, 0, 0); \
    acc[(M0)+3][0] = __builtin_amdgcn_mfma_f32_16x16x32_bf16(AC[3], BC[0], acc[(M0)+3][0], 0, 0, 0); \
    acc[(M0)+3][1] = __builtin_amdgcn_mfma_f32_16x16x32_bf16(AC[3], BC[1], acc[(M0)+3][1], 0, 0, 0); \
    acc[(M0)+3][2] = __builtin_amdgcn_mfma_f32_16x16x32_bf16(AC[3], BC[2], acc[(M0)+3][2], 0, 0, 0); \
    acc[(M0)+3][3] = __builtin_amdgcn_mfma_f32_16x16x32_bf16(AC[3], BC[3], acc[(M0)+3][3], 0, 0, 0); \
    __builtin_amdgcn_s_setprio(0);

#define TAIL_W6 { asm volatile("s_waitcnt vmcnt(6)" ::: "memory"); BAR; __builtin_amdgcn_sched_barrier(0); }
#define TAIL_W4 { asm volatile("s_waitcnt vmcnt(4)" ::: "memory"); BAR; __builtin_amdgcn_sched_barrier(0); }
#define TAIL_W0 { asm volatile("s_waitcnt vmcnt(0)" ::: "memory"); BAR; __builtin_amdgcn_sched_barrier(0); }

    // prologue: A/B(t0)kh0, A/B(t0)kh1, A/B(t1)kh0 (12 loads)
    STA(0, 0, 0); STB(0, 0, 0);
    STA(0, 1, 0); STB(0, 1, 0);
    STA(1, 0, 64); STB(1, 0, 64);
    asm volatile("s_waitcnt vmcnt(8)" ::: "memory");   // t0.kh0 landed
    BAR; __builtin_amdgcn_sched_barrier(0);
    LDAF(aX, 0, 0, 0); LDBF(bX, 0, 0);                 // frags for t0 P1

    // tile = 4 logical phases, 2 barriers (P1/P3 tails only -- see audit)
#define TILE(b, kc, S1, S2, S3, S4, T1, T3, P4B, P4LD) \
    S1; LDAF(aY, b, 0, 1);                    MF(aX, bX, 0); T1; \
    S2; LDBF(bY, b, 1); LDAF(aX, b, 1, 0);    MF(aY, bX, 4); \
    S3; LDAF(aY, b, 1, 1);                    MF(aX, bY, 0); T3; \
    S4; if (P4LD) { LDBF(bX, P4B, 0); LDAF(aX, P4B, 0, 0); } \
                                              MF(aY, bY, 4);

    int kb = 0;
#pragma unroll 1
    for (int tp = 0; tp < 7; ++tp, kb += 128) {
        TILE(0, kb, STA(1, 1, kb + 64), STB(1, 1, kb + 64),
                    STA(0, 0, kb + 128), STB(0, 0, kb + 128),
                    TAIL_W6, TAIL_W6, 1, 1)
        TILE(1, kb + 64, STA(0, 1, kb + 128), STB(0, 1, kb + 128),
                         STA(1, 0, kb + 192), STB(1, 0, kb + 192),
                         TAIL_W6, TAIL_W6, 0, 1)
    }
    TILE(0, 896, STA(1, 1, 960), STB(1, 1, 960), , ,
                 TAIL_W6, TAIL_W4, 1, 1)
    { const int b = 1;
      LDAF(aY, b, 0, 1);                    MF(aX, bX, 0); TAIL_W0;
      LDBF(bY, b, 1); LDAF(aX, b, 1, 0);    MF(aY, bX, 4);
      LDAF(aY, b, 1, 1);                    MF(aX, bY, 0);
                                            MF(aY, bY, 4);
    }

#undef TILE
#undef MF
#undef TAIL_W6
#undef TAIL_W4
#undef TAIL_W0
#undef LDA
#undef LDAF
#undef LDBF
#undef STA
#undef STB

#pragma unroll
    for (int m = 0; m < 8; m++) {
#pragma unroll
        for (int r = 0; r < 4; r++) {
            int row = m0 + wr * 128 + m * 16 + quad * 4 + r;
#pragma unroll
            for (int n = 0; n < 4; n++) {
                int col = n0 + wc * 64 + n * 16 + ln;
                float v = acc[m][n][r] + bias[col];
                if (col < 1024) v *= qmul;
                C[(size_t)row * 3072 + col] = (bf16_t)v;
            }
        }
    }
}

// ---------------------------------------------------------------- GEMM  C = A * B^T (+bias) (+resid)
// proj GEMM: R1 2-buffer 32KB __syncthreads structure.
__global__ __launch_bounds__(256, 3) void k_gemm_bt(
    const bf16_t* __restrict__ A, const bf16_t* __restrict__ Bm,
    const float* __restrict__ bias, const float* __restrict__ resid,
    bf16_t* __restrict__ Cb, float* __restrict__ Cf,
    int M, int N, int K, int qcols, float qmul)
{
    __shared__ bf16_t As[2][128 * 32];
    __shared__ bf16_t Bs[2][128 * 32];

    int nTile = N >> 7;
    int x = blockIdx.x & 7, g = blockIdx.x >> 3;
    int n_idx = g % nTile;
    int m_idx = (g / nTile) * 8 + x;
    int m0 = m_idx << 7;
    int n0 = n_idx << 7;
    int t = threadIdx.x;
    int w = t >> 6, lane = t & 63, quad = lane >> 4, ln = lane & 15;
    int wm = (w >> 1) << 6, wn = (w & 1) << 6;

    int srow = lane >> 2;                               // 0..15
    int scol = ((lane & 3) ^ ((lane >> 3) & 3)) << 3;   // swizzled logical chunk *8
    const bf16_t* Ag0 = A  + (size_t)(m0 + w * 16 +      srow) * K + scol;
    const bf16_t* Ag1 = A  + (size_t)(m0 + w * 16 + 64 + srow) * K + scol;
    const bf16_t* Bg0 = Bm + (size_t)(n0 + w * 16 +      srow) * K + scol;
    const bf16_t* Bg1 = Bm + (size_t)(n0 + w * 16 + 64 + srow) * K + scol;
    int lo0 = (w * 16) * 32, lo1 = (w * 16 + 64) * 32;

    v4f acc[4][4];
#pragma unroll
    for (int i = 0; i < 4; i++)
#pragma unroll
        for (int j = 0; j < 4; j++) acc[i][j] = (v4f){0.f, 0.f, 0.f, 0.f};

    // prologue: tile 0 -> buf 0
    GLD16(Ag0, &As[0][lo0]);
    GLD16(Ag1, &As[0][lo1]);
    GLD16(Bg0, &Bs[0][lo0]);
    GLD16(Bg1, &Bs[0][lo1]);

    int sw = (ln >> 1) & 3;   // read-side swizzle
    int buf = 0;
    for (int k0 = 0; k0 < K; k0 += 32, buf ^= 1) {
        __syncthreads();   // vmcnt(0) drain covers tile-k0 loads (in flight since k0-32)
        if (k0 + 32 < K) {
            GLD16(Ag0 + k0 + 32, &As[buf ^ 1][lo0]);
            GLD16(Ag1 + k0 + 32, &As[buf ^ 1][lo1]);
            GLD16(Bg0 + k0 + 32, &Bs[buf ^ 1][lo0]);
            GLD16(Bg1 + k0 + 32, &Bs[buf ^ 1][lo1]);
        }
        v8bf af[4], bfr[4];
#pragma unroll
        for (int mt = 0; mt < 4; mt++)
            af[mt] = *(const v8bf*)&As[buf][(wm + mt * 16 + ln) * 32 + ((quad ^ sw) << 3)];
#pragma unroll
        for (int nt = 0; nt < 4; nt++)
            bfr[nt] = *(const v8bf*)&Bs[buf][(wn + nt * 16 + ln) * 32 + ((quad ^ sw) << 3)];
#pragma unroll
        for (int mt = 0; mt < 4; mt++)
#pragma unroll
            for (int nt = 0; nt < 4; nt++)
                acc[mt][nt] = __builtin_amdgcn_mfma_f32_16x16x32_bf16(af[mt], bfr[nt], acc[mt][nt], 0, 0, 0);
    }

#pragma unroll
    for (int mt = 0; mt < 4; mt++) {
#pragma unroll
        for (int r = 0; r < 4; r++) {
            int row = m0 + wm + mt * 16 + quad * 4 + r;
#pragma unroll
            for (int nt = 0; nt < 4; nt++) {
                int col = n0 + wn + nt * 16 + ln;
                float v = acc[mt][nt][r] + bias[col];
                if (Cf) Cf[(size_t)row * N + col] = v + resid[(size_t)row * N + col];
                else {
                    if (col < qcols) v *= qmul;
                    Cb[(size_t)row * N + col] = (bf16_t)v;
                }
            }
        }
    }
}

// ---------------------------------------------------------------- V transpose: qkv V-cols -> Vt[bh][d][s]
__global__ __launch_bounds__(256) void k_transpose_v(const bf16_t* __restrict__ qkv,
                                                     bf16_t* __restrict__ vt) {
    __shared__ bf16_t tile[64 * 72];
    int bid = blockIdx.x;
    int st = bid & 31, bh = bid >> 5, b = bh >> 4, h = bh & 15;
    int t = threadIdx.x;
    const bf16_t* src = qkv + (size_t)(b * SEQ + st * 64) * 3072 + 2048 + h * 64;
#pragma unroll
    for (int i = 0; i < 2; i++) {
        int c = t + i * 256, row = c >> 3, c8 = (c & 7) << 3;
        *(uint4*)&tile[row * 72 + c8] = *(const uint4*)(src + (size_t)row * 3072 + c8);
    }
    __syncthreads();
    bf16_t* dst = vt + (size_t)bh * DHEAD * SEQ + st * 64;
#pragma unroll
    for (int i = 0; i < 2; i++) {
        int c = t + i * 256, d = c >> 3, s8 = (c & 7) << 3;
        v8bf o;
#pragma unroll
        for (int j = 0; j < 8; j++) o[j] = tile[(s8 + j) * 72 + d];
        *(v8bf*)(dst + (size_t)d * SEQ + s8) = o;
    }
}

// ---------------------------------------------------------------- attention (register-resident P)
// R9 structure: 2 q-tiles per block, 512 thr = 8 waves, K/V staged once
// per 256 q-rows; swizzles conflict-free (verified: 0 conflicts).
__global__ __launch_bounds__(512, 2) void k_attn(const bf16_t* __restrict__ qkv,
                                                 const bf16_t* __restrict__ vt,
                                                 bf16_t* __restrict__ attn) {
    __shared__ bf16_t Ks[2][64 * 64];
    __shared__ bf16_t Vs[2][64 * 64];

    int bid = blockIdx.x;
    int xcd = bid & 7, u = bid >> 3;
    int qt8 = u & 7;                    // 8 q-tiles of 256 rows
    int bh = ((u >> 3) << 3) | xcd;     // 8 bh-groups x 8 xcd = 64 bh
    int b = bh >> 4, h = bh & 15;
    int t = threadIdx.x, w = t >> 6, lane = t & 63, quad = lane >> 4, ln = lane & 15;
    int q0 = qt8 * 256 + w * 32;

    v8bf qf[2][2];
#pragma unroll
    for (int qs = 0; qs < 2; qs++) {
        const bf16_t* Qp = qkv + (size_t)(b * SEQ + q0 + qs * 16 + ln) * 3072 + h * 64 + quad * 8;
        qf[qs][0] = *(const v8bf*)Qp;
        qf[qs][1] = *(const v8bf*)(Qp + 32);
    }

    // staging: thread t covers tile-row tr = w*8 + (lane>>3), chunk lane&7
    int tr = w * 8 + (lane >> 3);
    int scolK = ((lane & 7) ^ ((lane >> 3) & 3) ^ ((w & 1) << 2)) << 3;
    int scolV = ((lane & 7) ^ (lane >> 3)) << 3;
    const bf16_t* Kg = qkv + (size_t)(b * SEQ + tr) * 3072 + 1024 + h * 64 + scolK;
    const bf16_t* Vg = vt + (size_t)bh * DHEAD * SEQ + (size_t)tr * SEQ + scolV;
    int ko = (w * 8) * 64;              // wave-uniform LDS base (elements)

    int gk = (ln & 3) | (((ln >> 2) & 1) << 2);
    int gv = ln & 7;
    int rrbase = ((ln >> 2) << 3) + (ln & 3);
    int o0 = (rrbase) * 64,       o1 = (rrbase + 4) * 64;
    int o2 = (rrbase + 32) * 64,  o3 = (rrbase + 36) * 64;

    const v4f z4 = (v4f){0.f, 0.f, 0.f, 0.f};
    v8bf ones8;
#pragma unroll
    for (int j = 0; j < 8; j++) ones8[j] = (bf16_t)1.0f;

    v4f o[2][4];
#pragma unroll
    for (int qs = 0; qs < 2; qs++)
#pragma unroll
        for (int d = 0; d < 4; d++) o[qs][d] = z4;
    v4f den[2] = {z4, z4};

    // prologue: tile 0 -> buf 0 (1 GLD16 K + 1 GLD16 V per thread)
    GLD16(Kg, &Ks[0][ko]);
    GLD16(Vg, &Vs[0][ko]);

    int buf = 0;
    for (int kt = 0; kt < SEQ; kt += 64, buf ^= 1) {
        __syncthreads();
        if (kt + 64 < SEQ) {
            GLD16(Kg + (size_t)(kt + 64) * 3072, &Ks[buf ^ 1][ko]);
            GLD16(Vg + kt + 64, &Vs[buf ^ 1][ko]);
        }

        const bf16_t* Kb = &Ks[buf][0];
        v4f s0[4], s1[4];
        int rof[4] = {o0, o1, o2, o3};
#pragma unroll
        for (int nt = 0; nt < 4; nt++) {
            v8bf kf0 = *(const v8bf*)&Kb[rof[nt] + ((quad ^ gk) << 3)];
            v8bf kf1 = *(const v8bf*)&Kb[rof[nt] + (((quad | 4) ^ gk) << 3)];
            s0[nt] = __builtin_amdgcn_mfma_f32_16x16x32_bf16(kf0, qf[0][0], z4, 0, 0, 0);
            s0[nt] = __builtin_amdgcn_mfma_f32_16x16x32_bf16(kf1, qf[0][1], s0[nt], 0, 0, 0);
            s1[nt] = __builtin_amdgcn_mfma_f32_16x16x32_bf16(kf0, qf[1][0], z4, 0, 0, 0);
            s1[nt] = __builtin_amdgcn_mfma_f32_16x16x32_bf16(kf1, qf[1][1], s1[nt], 0, 0, 0);
        }

#pragma unroll
        for (int tk = 0; tk < 2; tk++) {
            v8bf vfd[4];
#pragma unroll
            for (int d = 0; d < 4; d++)
                vfd[d] = *(const v8bf*)&Vs[buf][(d * 16 + ln) * 64 + (((tk * 4 + quad) ^ gv) << 3)];
#pragma unroll
            for (int qs = 0; qs < 2; qs++) {
                v4f* s = qs ? s1 : s0;
                float e0 = __builtin_amdgcn_exp2f(s[2 * tk][0]);
                float e1 = __builtin_amdgcn_exp2f(s[2 * tk][1]);
                float e2 = __builtin_amdgcn_exp2f(s[2 * tk][2]);
                float e3 = __builtin_amdgcn_exp2f(s[2 * tk][3]);
                float e4 = __builtin_amdgcn_exp2f(s[2 * tk + 1][0]);
                float e5 = __builtin_amdgcn_exp2f(s[2 * tk + 1][1]);
                float e6 = __builtin_amdgcn_exp2f(s[2 * tk + 1][2]);
                float e7 = __builtin_amdgcn_exp2f(s[2 * tk + 1][3]);
                v8bf pf;
                pf[0] = (bf16_t)e0; pf[1] = (bf16_t)e1; pf[2] = (bf16_t)e2; pf[3] = (bf16_t)e3;
                pf[4] = (bf16_t)e4; pf[5] = (bf16_t)e5; pf[6] = (bf16_t)e6; pf[7] = (bf16_t)e7;
                den[qs] = __builtin_amdgcn_mfma_f32_16x16x32_bf16(pf, ones8, den[qs], 0, 0, 0);
#pragma unroll
                for (int d = 0; d < 4; d++)
                    o[qs][d] = __builtin_amdgcn_mfma_f32_16x16x32_bf16(pf, vfd[d], o[qs][d], 0, 0, 0);
            }
        }
    }

#pragma unroll
    for (int qs = 0; qs < 2; qs++) {
        int rowg = b * SEQ + q0 + qs * 16;
#pragma unroll
        for (int r = 0; r < 4; r++) {
            float inv = 1.f / den[qs][r];
#pragma unroll
            for (int d = 0; d < 4; d++)
                attn[(size_t)(rowg + quad * 4 + r) * D_MODEL + h * 64 + d * 16 + ln] =
                    (bf16_t)(o[qs][d][r] * inv);
        }
    }
}

// ---------------------------------------------------------------- LayerNorm (one row / block)
__global__ __launch_bounds__(256) void k_layernorm(const float* __restrict__ y,
                                                   const float* __restrict__ g,
                                                   const float* __restrict__ beta,
                                                   float* __restrict__ out) {
    __shared__ float rs[4], rq[4];
    int row = blockIdx.x, t = threadIdx.x;
    int w = t >> 6, lane = t & 63;
    float4 v = ((const float4*)(y + (size_t)row * D_MODEL))[t];
    float s = v.x + v.y + v.z + v.w;
    float q = v.x * v.x + v.y * v.y + v.z * v.z + v.w * v.w;
#pragma unroll
    for (int off = 1; off < 64; off <<= 1) {
        s += __shfl_xor(s, off);
        q += __shfl_xor(q, off);
    }
    if (lane == 0) { rs[w] = s; rq[w] = q; }
    __syncthreads();
    s = rs[0] + rs[1] + rs[2] + rs[3];
    q = rq[0] + rq[1] + rq[2] + rq[3];
    float mu = s * (1.f / D_MODEL);
    float var = q * (1.f / D_MODEL) - mu * mu;
    float rstd = rsqrtf(var + 1e-5f);
    float4 gg = ((const float4*)g)[t];
    float4 bb = ((const float4*)beta)[t];
    float4 o;
    o.x = (v.x - mu) * rstd * gg.x + bb.x;
    o.y = (v.y - mu) * rstd * gg.y + bb.y;
    o.z = (v.z - mu) * rstd * gg.z + bb.z;
    o.w = (v.w - mu) * rstd * gg.w + bb.w;
    ((float4*)(out + (size_t)row * D_MODEL))[t] = o;
}

// ---------------------------------------------------------------- launch
extern "C" void kernel_launch(void* const* d_in, const int* in_sizes, int n_in,
                              void* d_out, int out_size, void* d_ws, size_t ws_size,
                              hipStream_t stream) {
    const float* batch = (const float*)d_in[0];
    const float* wq = (const float*)d_in[1];
    const float* bq = (const float*)d_in[2];
    const float* wk = (const float*)d_in[3];
    const float* bk = (const float*)d_in[4];
    const float* wv = (const float*)d_in[5];
    const float* bv = (const float*)d_in[6];
    const float* wo = (const float*)d_in[7];
    const float* bo = (const float*)d_in[8];
    const float* ln_g = (const float*)d_in[9];
    const float* ln_b = (const float*)d_in[10];
    float* out = (float*)d_out;

    char* ws = (char*)d_ws;
    size_t offXb   = 0;                                          // bf16 X (later Vt)
    size_t offWqkv = offXb + (size_t)ROWS * D_MODEL * 2;
    size_t offWo   = offWqkv + (size_t)3072 * 1024 * 2;
    size_t offBias = offWo + (size_t)1024 * 1024 * 2;
    size_t offQKV  = offBias + 3072 * 4;                         // bf16 qkv (later fp32 y)
    size_t offAttn = offQKV + (size_t)ROWS * 3072 * 2;
    size_t total   = offAttn + (size_t)ROWS * D_MODEL * 2;       // = 92,286,976
    if (ws_size < total) return;

    bf16_t* Xb   = (bf16_t*)(ws + offXb);
    bf16_t* Vt   = (bf16_t*)(ws + offXb);
    bf16_t* Wqkv = (bf16_t*)(ws + offWqkv);
    bf16_t* Wob  = (bf16_t*)(ws + offWo);
    float*  bqkv = (float*)(ws + offBias);
    bf16_t* qkv  = (bf16_t*)(ws + offQKV);
    float*  y    = (float*)(ws + offQKV);
    bf16_t* attn = (bf16_t*)(ws + offAttn);

    const float SC = 0.125f * 1.44269504088896f;  // 1/sqrt(64) * log2(e), folded into Q

    k_prep<<<2048, 256, 0, stream>>>(batch, wq, wk, wv, wo, bq, bk, bv,
                                     Xb, Wqkv, Wob, bqkv);
    k_gemm256<<<384, 512, 0, stream>>>(Xb, Wqkv, bqkv, qkv, SC);
    k_transpose_v<<<2048, 256, 0, stream>>>(qkv, Vt);
    k_attn<<<512, 512, 0, stream>>>(qkv, Vt, attn);
    k_gemm_bt<<<64 * 8, 256, 0, stream>>>(attn, Wob, bo, batch, nullptr, y,
                                          8192, 1024, 1024, 0, 1.0f);
    k_layernorm<<<8192, 256, 0, stream>>>(y, ln_g, ln_b, out);
}

// Round 11
// 278.663 us; speedup vs baseline: 1.0768x; 1.0376x over previous
//
#include <hip/hip_runtime.h>

typedef __bf16 bf16_t;
typedef __bf16 v8bf __attribute__((ext_vector_type(8)));
typedef __bf16 v4bf __attribute__((ext_vector_type(4)));
typedef float  v4f  __attribute__((ext_vector_type(4)));

#define D_MODEL 1024
#define NHEAD   16
#define DHEAD   64
#define SEQ     2048
#define BATCH   4
#define ROWS    (BATCH*SEQ)   // 8192

// async global->LDS, 16B per lane; LDS dest MUST be wave-uniform:
// HW writes base + lane*16 (guide §5: not a per-lane scatter).
#define GLD16(g, l) __builtin_amdgcn_global_load_lds( \
    (const __attribute__((address_space(1))) void*)(g), \
    (__attribute__((address_space(3))) void*)(l), 16, 0, 0)

#define BAR asm volatile("s_barrier" ::: "memory")

// ---------------------------------------------------------------- fused prep (casts + bias pack)
// grid-stride at 2048 blocks.
__global__ __launch_bounds__(256) void k_prep(const float* __restrict__ batch,
                                              const float* __restrict__ wq,
                                              const float* __restrict__ wk,
                                              const float* __restrict__ wv,
                                              const float* __restrict__ wo,
                                              const float* __restrict__ bq,
                                              const float* __restrict__ bk,
                                              const float* __restrict__ bv,
                                              bf16_t* __restrict__ Xb,
                                              bf16_t* __restrict__ Wqkv,
                                              bf16_t* __restrict__ Wob,
                                              float* __restrict__ bqkv) {
    int t = threadIdx.x;
    for (int bid = blockIdx.x; bid < 12300; bid += 2048) {
        const float* src; bf16_t* dst; int idx;
        if (bid < 8192)       { src = batch; dst = Xb;             idx = bid * 256 + t; }
        else if (bid < 9216)  { src = wq;    dst = Wqkv;           idx = (bid - 8192) * 256 + t; }
        else if (bid < 10240) { src = wk;    dst = Wqkv + 1048576; idx = (bid - 9216) * 256 + t; }
        else if (bid < 11264) { src = wv;    dst = Wqkv + 2097152; idx = (bid - 10240) * 256 + t; }
        else if (bid < 12288) { src = wo;    dst = Wob;            idx = (bid - 11264) * 256 + t; }
        else {
            int i = (bid - 12288) * 256 + t;   // 0..3071
            if (i < 1024) bqkv[i] = bq[i];
            else if (i < 2048) bqkv[i] = bk[i - 1024];
            else if (i < 3072) bqkv[i] = bv[i - 2048];
            continue;
        }
        float4 f = ((const float4*)src)[idx];
        v4bf o;
        o[0] = (bf16_t)f.x; o[1] = (bf16_t)f.y; o[2] = (bf16_t)f.z; o[3] = (bf16_t)f.w;
        ((v4bf*)dst)[idx] = o;
    }
}

// ---------------------------------------------------------------- 256x256 pipelined GEMM -- Q,K ONLY
// R11: N=2048 (Q,K cols) -> grid 32m x 8n = 256 blocks = EXACTLY 1/CU,
// one balanced round (the old N=3072/384-block version ran 2 rounds for
// 1.5 rounds of work = 25% idle). V moved to k_gemm_vt. Schedule/swizzle
// identical to R10 (2 barriers/tile, counted vmcnt, 0 conflicts).
__global__ __launch_bounds__(512, 2) void k_gemm256(
    const bf16_t* __restrict__ A, const bf16_t* __restrict__ Bm,
    const float* __restrict__ bias, bf16_t* __restrict__ C, float qmul)
{
    __shared__ bf16_t As[2][2][256 * 32];
    __shared__ bf16_t Bs[2][2][256 * 32];

    const int K = 1024;
    int bid = blockIdx.x;
    int wg = (bid & 7) * 32 + (bid >> 3);      // XCD-chunked: 256 = 8 x 32
    int m_idx = wg >> 3, n_idx = wg & 7;       // 32 m x 8 n
    int m0 = m_idx << 8, n0 = n_idx << 8;

    int t = threadIdx.x;
    int lane = t & 63, quad = lane >> 4, ln = lane & 15;
    int w = t >> 6, wr = w >> 2, wc = w & 3;

    int cl = (t & 3) ^ ((t >> 3) & 3);
    const bf16_t* Ag = A  + (size_t)(m0 + (t >> 2)) * K + cl * 8;
    const bf16_t* Bg = Bm + (size_t)(n0 + (t >> 2)) * K + cl * 8;
    int wb = w << 9;                            // wave-uniform LDS base

#define STA(bufv, khv, kc) { const bf16_t* g_ = Ag + (kc) + ((khv) << 5); \
    GLD16(g_, &As[bufv][khv][wb]); GLD16(g_ + 131072, &As[bufv][khv][wb + 4096]); }
#define STB(bufv, khv, kc) { const bf16_t* g_ = Bg + (kc) + ((khv) << 5); \
    GLD16(g_, &Bs[bufv][khv][wb]); GLD16(g_ + 131072, &Bs[bufv][khv][wb + 4096]); }

    int rsw = (quad ^ ((ln >> 1) & 3)) << 3;
    int aofs = (wr * 128 + ln) * 32 + rsw;
    int bofs = (wc * 64 + ln) * 32 + rsw;

#define LDA(dst, bufv, mhv) { \
    dst[0] = *(const v8bf*)&AB_[aofs + (mhv) * 2048]; \
    dst[1] = *(const v8bf*)&AB_[aofs + (mhv) * 2048 + 512]; \
    dst[2] = *(const v8bf*)&AB_[aofs + (mhv) * 2048 + 1024]; \
    dst[3] = *(const v8bf*)&AB_[aofs + (mhv) * 2048 + 1536]; }
#define LDAF(dst, bufv, khv, mhv) { const bf16_t* AB_ = &As[bufv][khv][0]; LDA(dst, bufv, mhv) }
#define LDBF(dst, bufv, khv) { const bf16_t* BB_ = &Bs[bufv][khv][0]; \
    dst[0] = *(const v8bf*)&BB_[bofs]; \
    dst[1] = *(const v8bf*)&BB_[bofs + 512]; \
    dst[2] = *(const v8bf*)&BB_[bofs + 1024]; \
    dst[3] = *(const v8bf*)&BB_[bofs + 1536]; }

    v4f acc[8][4];
#pragma unroll
    for (int i = 0; i < 8; i++)
#pragma unroll
        for (int j = 0; j < 4; j++) acc[i][j] = (v4f){0.f, 0.f, 0.f, 0.f};

    v8bf aX[4], aY[4], bX[4], bY[4];

#define MF(AC, BC, M0) \
    __builtin_amdgcn_s_setprio(1); \
    acc[(M0)+0][0] = __builtin_amdgcn_mfma_f32_16x16x32_bf16(AC[0], BC[0], acc[(M0)+0][0], 0, 0, 0); \
    acc[(M0)+0][1] = __builtin_amdgcn_mfma_f32_16x16x32_bf16(AC[0], BC[1], acc[(M0)+0][1], 0, 0, 0); \
    acc[(M0)+0][2] = __builtin_amdgcn_mfma_f32_16x16x32_bf16(AC[0], BC[2], acc[(M0)+0][2], 0, 0, 0); \
    acc[(M0)+0][3] = __builtin_amdgcn_mfma_f32_16x16x32_bf16(AC[0], BC[3], acc[(M0)+0][3], 0, 0, 0); \
    acc[(M0)+1][0] = __builtin_amdgcn_mfma_f32_16x16x32_bf16(AC[1], BC[0], acc[(M0)+1][0], 0, 0, 0); \
    acc[(M0)+1][1] = __builtin_amdgcn_mfma_f32_16x16x32_bf16(AC[1], BC[1], acc[(M0)+1][1], 0, 0, 0); \
    acc[(M0)+1][2] = __builtin_amdgcn_mfma_f32_16x16x32_bf16(AC[1], BC[2], acc[(M0)+1][2], 0, 0, 0); \
    acc[(M0)+1][3] = __builtin_amdgcn_mfma_f32_16x16x32_bf16(AC[1], BC[3], acc[(M0)+1][3], 0, 0, 0); \
    acc[(M0)+2][0] = __builtin_amdgcn_mfma_f32_16x16x32_bf16(AC[2], BC[0], acc[(M0)+2][0], 0, 0, 0); \
    acc[(M0)+2][1] = __builtin_amdgcn_mfma_f32_16x16x32_bf16(AC[2], BC[1], acc[(M0)+2][1], 0, 0, 0); \
    acc[(M0)+2][2] = __builtin_amdgcn_mfma_f32_16x16x32_bf16(AC[2], BC[2], acc[(M0)+2][2], 0, 0, 0); \
    acc[(M0)+2][3] = __builtin_amdgcn_mfma_f32_16x16x32_bf16(AC[2], BC[3], acc[(M0)+2][3], 0, 0, 0); \
    acc[(M0)+3][0] = __builtin_amdgcn_mfma_f32_16x16x32_bf16(AC[3], BC[0], acc[(M0)+3][0], 0, 0, 0); \
    acc[(M0)+3][1] = __builtin_amdgcn_mfma_f32_16x16x32_bf16(AC[3], BC[1], acc[(M0)+3][1], 0, 0, 0); \
    acc[(M0)+3][2] = __builtin_amdgcn_mfma_f32_16x16x32_bf16(AC[3], BC[2], acc[(M0)+3][2], 0, 0, 0); \
    acc[(M0)+3][3] = __builtin_amdgcn_mfma_f32_16x16x32_bf16(AC[3], BC[3], acc[(M0)+3][3], 0, 0, 0); \
    __builtin_amdgcn_s_setprio(0);

#define TAIL_W6 { asm volatile("s_waitcnt vmcnt(6)" ::: "memory"); BAR; __builtin_amdgcn_sched_barrier(0); }
#define TAIL_W4 { asm volatile("s_waitcnt vmcnt(4)" ::: "memory"); BAR; __builtin_amdgcn_sched_barrier(0); }
#define TAIL_W0 { asm volatile("s_waitcnt vmcnt(0)" ::: "memory"); BAR; __builtin_amdgcn_sched_barrier(0); }

    // prologue: A/B(t0)kh0, A/B(t0)kh1, A/B(t1)kh0 (12 loads)
    STA(0, 0, 0); STB(0, 0, 0);
    STA(0, 1, 0); STB(0, 1, 0);
    STA(1, 0, 64); STB(1, 0, 64);
    asm volatile("s_waitcnt vmcnt(8)" ::: "memory");   // t0.kh0 landed
    BAR; __builtin_amdgcn_sched_barrier(0);
    LDAF(aX, 0, 0, 0); LDBF(bX, 0, 0);                 // frags for t0 P1

    // tile = 4 logical phases, 2 barriers (P1/P3 tails; audit in R10)
#define TILE(b, kc, S1, S2, S3, S4, T1, T3, P4B, P4LD) \
    S1; LDAF(aY, b, 0, 1);                    MF(aX, bX, 0); T1; \
    S2; LDBF(bY, b, 1); LDAF(aX, b, 1, 0);    MF(aY, bX, 4); \
    S3; LDAF(aY, b, 1, 1);                    MF(aX, bY, 0); T3; \
    S4; if (P4LD) { LDBF(bX, P4B, 0); LDAF(aX, P4B, 0, 0); } \
                                              MF(aY, bY, 4);

    int kb = 0;
#pragma unroll 1
    for (int tp = 0; tp < 7; ++tp, kb += 128) {
        TILE(0, kb, STA(1, 1, kb + 64), STB(1, 1, kb + 64),
                    STA(0, 0, kb + 128), STB(0, 0, kb + 128),
                    TAIL_W6, TAIL_W6, 1, 1)
        TILE(1, kb + 64, STA(0, 1, kb + 128), STB(0, 1, kb + 128),
                         STA(1, 0, kb + 192), STB(1, 0, kb + 192),
                         TAIL_W6, TAIL_W6, 0, 1)
    }
    TILE(0, 896, STA(1, 1, 960), STB(1, 1, 960), , ,
                 TAIL_W6, TAIL_W4, 1, 1)
    { const int b = 1;
      LDAF(aY, b, 0, 1);                    MF(aX, bX, 0); TAIL_W0;
      LDBF(bY, b, 1); LDAF(aX, b, 1, 0);    MF(aY, bX, 4);
      LDAF(aY, b, 1, 1);                    MF(aX, bY, 0);
                                            MF(aY, bY, 4);
    }

#undef TILE
#undef MF
#undef TAIL_W6
#undef TAIL_W4
#undef TAIL_W0
#undef LDA
#undef LDAF
#undef LDBF
#undef STA
#undef STB

    // C = qk[8192][2048]
#pragma unroll
    for (int m = 0; m < 8; m++) {
#pragma unroll
        for (int r = 0; r < 4; r++) {
            int row = m0 + wr * 128 + m * 16 + quad * 4 + r;
#pragma unroll
            for (int n = 0; n < 4; n++) {
                int col = n0 + wc * 64 + n * 16 + ln;
                float v = acc[m][n][r] + bias[col];
                if (col < 1024) v *= qmul;
                C[(size_t)row * 2048 + col] = (bf16_t)v;
            }
        }
    }
}

// ---------------------------------------------------------------- V GEMM with TRANSPOSED epilogue
// R11: computes V = X @ Wv^T + bv (M=8192, N=1024, K=1024) on the proven
// 128x128 2-buffer structure, and writes directly to Vt[bh][d][s] via an
// LDS bounce (replaces the whole k_transpose_v kernel + its launch).
// Bounce: 128x128 bf16 tile in SH (32KB, reuses staging LDS) with XOR
// swizzle d' = d ^ (((s>>3)&15)<<1). Read-phase bank (8-lane group) =
// (d/2) ^ t over lanes -> distinct = conflict-free; write phase scalar.
__global__ __launch_bounds__(256, 3) void k_gemm_vt(
    const bf16_t* __restrict__ A, const bf16_t* __restrict__ Bm,
    const float* __restrict__ bias, bf16_t* __restrict__ vt)
{
    __shared__ bf16_t SH[4][128 * 32];          // staging: A=SH[0..1], B=SH[2..3]
    const int K = 1024, N = 1024;

    int nTile = N >> 7;                          // 8
    int x = blockIdx.x & 7, g = blockIdx.x >> 3;
    int n_idx = g % nTile;
    int m_idx = (g / nTile) * 8 + x;
    int m0 = m_idx << 7;
    int n0 = n_idx << 7;
    int t = threadIdx.x;
    int w = t >> 6, lane = t & 63, quad = lane >> 4, ln = lane & 15;
    int wm = (w >> 1) << 6, wn = (w & 1) << 6;

    int srow = lane >> 2;                               // 0..15
    int scol = ((lane & 3) ^ ((lane >> 3) & 3)) << 3;   // swizzled logical chunk *8
    const bf16_t* Ag0 = A  + (size_t)(m0 + w * 16 +      srow) * K + scol;
    const bf16_t* Ag1 = A  + (size_t)(m0 + w * 16 + 64 + srow) * K + scol;
    const bf16_t* Bg0 = Bm + (size_t)(n0 + w * 16 +      srow) * K + scol;
    const bf16_t* Bg1 = Bm + (size_t)(n0 + w * 16 + 64 + srow) * K + scol;
    int lo0 = (w * 16) * 32, lo1 = (w * 16 + 64) * 32;

    v4f acc[4][4];
#pragma unroll
    for (int i = 0; i < 4; i++)
#pragma unroll
        for (int j = 0; j < 4; j++) acc[i][j] = (v4f){0.f, 0.f, 0.f, 0.f};

    GLD16(Ag0, &SH[0][lo0]);
    GLD16(Ag1, &SH[0][lo1]);
    GLD16(Bg0, &SH[2][lo0]);
    GLD16(Bg1, &SH[2][lo1]);

    int sw = (ln >> 1) & 3;   // read-side swizzle
    int buf = 0;
    for (int k0 = 0; k0 < K; k0 += 32, buf ^= 1) {
        __syncthreads();
        if (k0 + 32 < K) {
            GLD16(Ag0 + k0 + 32, &SH[buf ^ 1][lo0]);
            GLD16(Ag1 + k0 + 32, &SH[buf ^ 1][lo1]);
            GLD16(Bg0 + k0 + 32, &SH[2 + (buf ^ 1)][lo0]);
            GLD16(Bg1 + k0 + 32, &SH[2 + (buf ^ 1)][lo1]);
        }
        v8bf af[4], bfr[4];
#pragma unroll
        for (int mt = 0; mt < 4; mt++)
            af[mt] = *(const v8bf*)&SH[buf][(wm + mt * 16 + ln) * 32 + ((quad ^ sw) << 3)];
#pragma unroll
        for (int nt = 0; nt < 4; nt++)
            bfr[nt] = *(const v8bf*)&SH[2 + buf][(wn + nt * 16 + ln) * 32 + ((quad ^ sw) << 3)];
#pragma unroll
        for (int mt = 0; mt < 4; mt++)
#pragma unroll
            for (int nt = 0; nt < 4; nt++)
                acc[mt][nt] = __builtin_amdgcn_mfma_f32_16x16x32_bf16(af[mt], bfr[nt], acc[mt][nt], 0, 0, 0);
    }

    // ---- transposed epilogue via LDS bounce ----
    __syncthreads();                              // all waves done reading staging
    bf16_t* P = &SH[0][0];                        // 128x128 bf16 = 32KB
#pragma unroll
    for (int mt = 0; mt < 4; mt++) {
#pragma unroll
        for (int r = 0; r < 4; r++) {
            int s_loc = wm + mt * 16 + quad * 4 + r;
            int swz = ((s_loc >> 3) & 15) << 1;
#pragma unroll
            for (int nt = 0; nt < 4; nt++) {
                int d_loc = wn + nt * 16 + ln;
                float v = acc[mt][nt][r] + bias[n0 + d_loc];
                P[s_loc * 128 + (d_loc ^ swz)] = (bf16_t)v;
            }
        }
    }
    __syncthreads();
    // read transposed + store: vt[bh][dh][s], 16B coalesced along s
    int b = m0 >> 11, sBase = m0 & 2047;
#pragma unroll
    for (int i = 0; i < 8; i++) {
        int gidx = t + i * 256;                   // 0..2047 v8bf units
        int d = gidx >> 4;                        // block-local col 0..127
        int s0 = (gidx & 15) << 3;                // 0..120
        v8bf o;
#pragma unroll
        for (int j = 0; j < 8; j++) {
            int s = s0 + j;
            o[j] = P[s * 128 + (d ^ (((s >> 3) & 15) << 1))];
        }
        int col = n0 + d;
        int h = col >> 6, dh = col & 63;
        *(v8bf*)(vt + (size_t)(b * 16 + h) * DHEAD * SEQ + (size_t)dh * SEQ + sBase + s0) = o;
    }
}

// ---------------------------------------------------------------- GEMM  C = A * B^T (+bias) (+resid)
// proj GEMM: R1 2-buffer 32KB __syncthreads structure.
__global__ __launch_bounds__(256, 3) void k_gemm_bt(
    const bf16_t* __restrict__ A, const bf16_t* __restrict__ Bm,
    const float* __restrict__ bias, const float* __restrict__ resid,
    bf16_t* __restrict__ Cb, float* __restrict__ Cf,
    int M, int N, int K, int qcols, float qmul)
{
    __shared__ bf16_t As[2][128 * 32];
    __shared__ bf16_t Bs[2][128 * 32];

    int nTile = N >> 7;
    int x = blockIdx.x & 7, g = blockIdx.x >> 3;
    int n_idx = g % nTile;
    int m_idx = (g / nTile) * 8 + x;
    int m0 = m_idx << 7;
    int n0 = n_idx << 7;
    int t = threadIdx.x;
    int w = t >> 6, lane = t & 63, quad = lane >> 4, ln = lane & 15;
    int wm = (w >> 1) << 6, wn = (w & 1) << 6;

    int srow = lane >> 2;                               // 0..15
    int scol = ((lane & 3) ^ ((lane >> 3) & 3)) << 3;   // swizzled logical chunk *8
    const bf16_t* Ag0 = A  + (size_t)(m0 + w * 16 +      srow) * K + scol;
    const bf16_t* Ag1 = A  + (size_t)(m0 + w * 16 + 64 + srow) * K + scol;
    const bf16_t* Bg0 = Bm + (size_t)(n0 + w * 16 +      srow) * K + scol;
    const bf16_t* Bg1 = Bm + (size_t)(n0 + w * 16 + 64 + srow) * K + scol;
    int lo0 = (w * 16) * 32, lo1 = (w * 16 + 64) * 32;

    v4f acc[4][4];
#pragma unroll
    for (int i = 0; i < 4; i++)
#pragma unroll
        for (int j = 0; j < 4; j++) acc[i][j] = (v4f){0.f, 0.f, 0.f, 0.f};

    // prologue: tile 0 -> buf 0
    GLD16(Ag0, &As[0][lo0]);
    GLD16(Ag1, &As[0][lo1]);
    GLD16(Bg0, &Bs[0][lo0]);
    GLD16(Bg1, &Bs[0][lo1]);

    int sw = (ln >> 1) & 3;   // read-side swizzle
    int buf = 0;
    for (int k0 = 0; k0 < K; k0 += 32, buf ^= 1) {
        __syncthreads();
        if (k0 + 32 < K) {
            GLD16(Ag0 + k0 + 32, &As[buf ^ 1][lo0]);
            GLD16(Ag1 + k0 + 32, &As[buf ^ 1][lo1]);
            GLD16(Bg0 + k0 + 32, &Bs[buf ^ 1][lo0]);
            GLD16(Bg1 + k0 + 32, &Bs[buf ^ 1][lo1]);
        }
        v8bf af[4], bfr[4];
#pragma unroll
        for (int mt = 0; mt < 4; mt++)
            af[mt] = *(const v8bf*)&As[buf][(wm + mt * 16 + ln) * 32 + ((quad ^ sw) << 3)];
#pragma unroll
        for (int nt = 0; nt < 4; nt++)
            bfr[nt] = *(const v8bf*)&Bs[buf][(wn + nt * 16 + ln) * 32 + ((quad ^ sw) << 3)];
#pragma unroll
        for (int mt = 0; mt < 4; mt++)
#pragma unroll
            for (int nt = 0; nt < 4; nt++)
                acc[mt][nt] = __builtin_amdgcn_mfma_f32_16x16x32_bf16(af[mt], bfr[nt], acc[mt][nt], 0, 0, 0);
    }

#pragma unroll
    for (int mt = 0; mt < 4; mt++) {
#pragma unroll
        for (int r = 0; r < 4; r++) {
            int row = m0 + wm + mt * 16 + quad * 4 + r;
#pragma unroll
            for (int nt = 0; nt < 4; nt++) {
                int col = n0 + wn + nt * 16 + ln;
                float v = acc[mt][nt][r] + bias[col];
                if (Cf) Cf[(size_t)row * N + col] = v + resid[(size_t)row * N + col];
                else {
                    if (col < qcols) v *= qmul;
                    Cb[(size_t)row * N + col] = (bf16_t)v;
                }
            }
        }
    }
}

// ---------------------------------------------------------------- attention (register-resident P)
// R9 structure; R11: qk row stride 3072 -> 2048 (Q cols 0..1023, K cols
// 1024..2047); Vt is now a dedicated buffer (same [bh][d][s] layout).
__global__ __launch_bounds__(512, 2) void k_attn(const bf16_t* __restrict__ qk,
                                                 const bf16_t* __restrict__ vt,
                                                 bf16_t* __restrict__ attn) {
    __shared__ bf16_t Ks[2][64 * 64];
    __shared__ bf16_t Vs[2][64 * 64];

    int bid = blockIdx.x;
    int xcd = bid & 7, u = bid >> 3;
    int qt8 = u & 7;                    // 8 q-tiles of 256 rows
    int bh = ((u >> 3) << 3) | xcd;     // 8 bh-groups x 8 xcd = 64 bh
    int b = bh >> 4, h = bh & 15;
    int t = threadIdx.x, w = t >> 6, lane = t & 63, quad = lane >> 4, ln = lane & 15;
    int q0 = qt8 * 256 + w * 32;

    v8bf qf[2][2];
#pragma unroll
    for (int qs = 0; qs < 2; qs++) {
        const bf16_t* Qp = qk + (size_t)(b * SEQ + q0 + qs * 16 + ln) * 2048 + h * 64 + quad * 8;
        qf[qs][0] = *(const v8bf*)Qp;
        qf[qs][1] = *(const v8bf*)(Qp + 32);
    }

    // staging: thread t covers tile-row tr = w*8 + (lane>>3), chunk lane&7
    int tr = w * 8 + (lane >> 3);
    int scolK = ((lane & 7) ^ ((lane >> 3) & 3) ^ ((w & 1) << 2)) << 3;
    int scolV = ((lane & 7) ^ (lane >> 3)) << 3;
    const bf16_t* Kg = qk + (size_t)(b * SEQ + tr) * 2048 + 1024 + h * 64 + scolK;
    const bf16_t* Vg = vt + (size_t)bh * DHEAD * SEQ + (size_t)tr * SEQ + scolV;
    int ko = (w * 8) * 64;              // wave-uniform LDS base (elements)

    int gk = (ln & 3) | (((ln >> 2) & 1) << 2);
    int gv = ln & 7;
    int rrbase = ((ln >> 2) << 3) + (ln & 3);
    int o0 = (rrbase) * 64,       o1 = (rrbase + 4) * 64;
    int o2 = (rrbase + 32) * 64,  o3 = (rrbase + 36) * 64;

    const v4f z4 = (v4f){0.f, 0.f, 0.f, 0.f};
    v8bf ones8;
#pragma unroll
    for (int j = 0; j < 8; j++) ones8[j] = (bf16_t)1.0f;

    v4f o[2][4];
#pragma unroll
    for (int qs = 0; qs < 2; qs++)
#pragma unroll
        for (int d = 0; d < 4; d++) o[qs][d] = z4;
    v4f den[2] = {z4, z4};

    // prologue: tile 0 -> buf 0 (1 GLD16 K + 1 GLD16 V per thread)
    GLD16(Kg, &Ks[0][ko]);
    GLD16(Vg, &Vs[0][ko]);

    int buf = 0;
    for (int kt = 0; kt < SEQ; kt += 64, buf ^= 1) {
        __syncthreads();
        if (kt + 64 < SEQ) {
            GLD16(Kg + (size_t)(kt + 64) * 2048, &Ks[buf ^ 1][ko]);
            GLD16(Vg + kt + 64, &Vs[buf ^ 1][ko]);
        }

        const bf16_t* Kb = &Ks[buf][0];
        v4f s0[4], s1[4];
        int rof[4] = {o0, o1, o2, o3};
#pragma unroll
        for (int nt = 0; nt < 4; nt++) {
            v8bf kf0 = *(const v8bf*)&Kb[rof[nt] + ((quad ^ gk) << 3)];
            v8bf kf1 = *(const v8bf*)&Kb[rof[nt] + (((quad | 4) ^ gk) << 3)];
            s0[nt] = __builtin_amdgcn_mfma_f32_16x16x32_bf16(kf0, qf[0][0], z4, 0, 0, 0);
            s0[nt] = __builtin_amdgcn_mfma_f32_16x16x32_bf16(kf1, qf[0][1], s0[nt], 0, 0, 0);
            s1[nt] = __builtin_amdgcn_mfma_f32_16x16x32_bf16(kf0, qf[1][0], z4, 0, 0, 0);
            s1[nt] = __builtin_amdgcn_mfma_f32_16x16x32_bf16(kf1, qf[1][1], s1[nt], 0, 0, 0);
        }

#pragma unroll
        for (int tk = 0; tk < 2; tk++) {
            v8bf vfd[4];
#pragma unroll
            for (int d = 0; d < 4; d++)
                vfd[d] = *(const v8bf*)&Vs[buf][(d * 16 + ln) * 64 + (((tk * 4 + quad) ^ gv) << 3)];
#pragma unroll
            for (int qs = 0; qs < 2; qs++) {
                v4f* s = qs ? s1 : s0;
                float e0 = __builtin_amdgcn_exp2f(s[2 * tk][0]);
                float e1 = __builtin_amdgcn_exp2f(s[2 * tk][1]);
                float e2 = __builtin_amdgcn_exp2f(s[2 * tk][2]);
                float e3 = __builtin_amdgcn_exp2f(s[2 * tk][3]);
                float e4 = __builtin_amdgcn_exp2f(s[2 * tk + 1][0]);
                float e5 = __builtin_amdgcn_exp2f(s[2 * tk + 1][1]);
                float e6 = __builtin_amdgcn_exp2f(s[2 * tk + 1][2]);
                float e7 = __builtin_amdgcn_exp2f(s[2 * tk + 1][3]);
                v8bf pf;
                pf[0] = (bf16_t)e0; pf[1] = (bf16_t)e1; pf[2] = (bf16_t)e2; pf[3] = (bf16_t)e3;
                pf[4] = (bf16_t)e4; pf[5] = (bf16_t)e5; pf[6] = (bf16_t)e6; pf[7] = (bf16_t)e7;
                den[qs] = __builtin_amdgcn_mfma_f32_16x16x32_bf16(pf, ones8, den[qs], 0, 0, 0);
#pragma unroll
                for (int d = 0; d < 4; d++)
                    o[qs][d] = __builtin_amdgcn_mfma_f32_16x16x32_bf16(pf, vfd[d], o[qs][d], 0, 0, 0);
            }
        }
    }

#pragma unroll
    for (int qs = 0; qs < 2; qs++) {
        int rowg = b * SEQ + q0 + qs * 16;
#pragma unroll
        for (int r = 0; r < 4; r++) {
            float inv = 1.f / den[qs][r];
#pragma unroll
            for (int d = 0; d < 4; d++)
                attn[(size_t)(rowg + quad * 4 + r) * D_MODEL + h * 64 + d * 16 + ln] =
                    (bf16_t)(o[qs][d][r] * inv);
        }
    }
}

// ---------------------------------------------------------------- LayerNorm (one row / block)
__global__ __launch_bounds__(256) void k_layernorm(const float* __restrict__ y,
                                                   const float* __restrict__ g,
                                                   const float* __restrict__ beta,
                                                   float* __restrict__ out) {
    __shared__ float rs[4], rq[4];
    int row = blockIdx.x, t = threadIdx.x;
    int w = t >> 6, lane = t & 63;
    float4 v = ((const float4*)(y + (size_t)row * D_MODEL))[t];
    float s = v.x + v.y + v.z + v.w;
    float q = v.x * v.x + v.y * v.y + v.z * v.z + v.w * v.w;
#pragma unroll
    for (int off = 1; off < 64; off <<= 1) {
        s += __shfl_xor(s, off);
        q += __shfl_xor(q, off);
    }
    if (lane == 0) { rs[w] = s; rq[w] = q; }
    __syncthreads();
    s = rs[0] + rs[1] + rs[2] + rs[3];
    q = rq[0] + rq[1] + rq[2] + rq[3];
    float mu = s * (1.f / D_MODEL);
    float var = q * (1.f / D_MODEL) - mu * mu;
    float rstd = rsqrtf(var + 1e-5f);
    float4 gg = ((const float4*)g)[t];
    float4 bb = ((const float4*)beta)[t];
    float4 o;
    o.x = (v.x - mu) * rstd * gg.x + bb.x;
    o.y = (v.y - mu) * rstd * gg.y + bb.y;
    o.z = (v.z - mu) * rstd * gg.z + bb.z;
    o.w = (v.w - mu) * rstd * gg.w + bb.w;
    ((float4*)(out + (size_t)row * D_MODEL))[t] = o;
}

// ---------------------------------------------------------------- launch
extern "C" void kernel_launch(void* const* d_in, const int* in_sizes, int n_in,
                              void* d_out, int out_size, void* d_ws, size_t ws_size,
                              hipStream_t stream) {
    const float* batch = (const float*)d_in[0];
    const float* wq = (const float*)d_in[1];
    const float* bq = (const float*)d_in[2];
    const float* wk = (const float*)d_in[3];
    const float* bk = (const float*)d_in[4];
    const float* wv = (const float*)d_in[5];
    const float* bv = (const float*)d_in[6];
    const float* wo = (const float*)d_in[7];
    const float* bo = (const float*)d_in[8];
    const float* ln_g = (const float*)d_in[9];
    const float* ln_b = (const float*)d_in[10];
    float* out = (float*)d_out;

    char* ws = (char*)d_ws;
    size_t offXb   = 0;                                          // bf16 X
    size_t offWqkv = offXb + (size_t)ROWS * D_MODEL * 2;
    size_t offWo   = offWqkv + (size_t)3072 * 1024 * 2;
    size_t offBias = offWo + (size_t)1024 * 1024 * 2;
    size_t offQK   = offBias + 3072 * 4;                         // bf16 qk [8192][2048] (later fp32 y)
    size_t offVt   = offQK + (size_t)ROWS * 2048 * 2;            // bf16 Vt [64][64][2048]
    size_t offAttn = offVt + (size_t)64 * DHEAD * SEQ * 2;
    size_t total   = offAttn + (size_t)ROWS * D_MODEL * 2;       // = 92,286,976 (unchanged)
    if (ws_size < total) return;

    bf16_t* Xb   = (bf16_t*)(ws + offXb);
    bf16_t* Wqkv = (bf16_t*)(ws + offWqkv);
    bf16_t* Wob  = (bf16_t*)(ws + offWo);
    float*  bqkv = (float*)(ws + offBias);
    bf16_t* qk   = (bf16_t*)(ws + offQK);
    float*  y    = (float*)(ws + offQK);                         // aliases qk (dead after attn)
    bf16_t* Vt   = (bf16_t*)(ws + offVt);
    bf16_t* attn = (bf16_t*)(ws + offAttn);

    const float SC = 0.125f * 1.44269504088896f;  // 1/sqrt(64) * log2(e), folded into Q

    k_prep<<<2048, 256, 0, stream>>>(batch, wq, wk, wv, wo, bq, bk, bv,
                                     Xb, Wqkv, Wob, bqkv);
    k_gemm256<<<256, 512, 0, stream>>>(Xb, Wqkv, bqkv, qk, SC);
    k_gemm_vt<<<64 * 8, 256, 0, stream>>>(Xb, Wqkv + 2097152, bqkv + 2048, Vt);
    k_attn<<<512, 512, 0, stream>>>(qk, Vt, attn);
    k_gemm_bt<<<64 * 8, 256, 0, stream>>>(attn, Wob, bo, batch, nullptr, y,
                                          8192, 1024, 1024, 0, 1.0f);
    k_layernorm<<<8192, 256, 0, stream>>>(y, ln_g, ln_b, out);
}